// Round 9
// baseline (273.199 us; speedup 1.0000x reference)
//
#include <hip/hip_runtime.h>
#include <hip/hip_fp16.h>
#include <math.h>

#define NNODES 50000
#define NEDGES 400000
#define INC    128
#define HC1    256   // HEADS*HID
#define NHEADS 8
#define OUTC   64
#define NK     16
#define NEG_SLOPE 0.2f
#define EPS_F  1e-16f

typedef unsigned short u16;
typedef __attribute__((ext_vector_type(8))) short bf16x8;
typedef __attribute__((ext_vector_type(4))) float f32x4;

__device__ __forceinline__ float lrelu(float x){ return x > 0.f ? x : NEG_SLOPE * x; }
__device__ __forceinline__ float eluf(float x){ return x > 0.f ? x : (__expf(x) - 1.f); }
__device__ __forceinline__ float bf2f(u16 v){ return __uint_as_float((unsigned)v << 16); }
__device__ __forceinline__ u16 f2bf(float f){
    unsigned u = __float_as_uint(f);
    unsigned r = (u + 0x7FFFu + ((u >> 16) & 1u)) >> 16;   // RTNE
    return (u16)r;
}
__device__ __forceinline__ short f2bf_s(float f){ return (short)f2bf(f); }
__device__ __forceinline__ u16 f2h(float f){ return __half_as_ushort(__float2half(f)); }
__device__ __forceinline__ float h2f(u16 v){ return __half2float(__ushort_as_half(v)); }

// one-instruction f16*f32+f32 MAC (no unpack)
__device__ __forceinline__ void fmix_lo(float& acc, unsigned w, float a){
    asm("v_fma_mix_f32 %0, %1, %2, %0 op_sel:[0,0,0] op_sel_hi:[1,0,0]"
        : "+v"(acc) : "v"(w), "v"(a));
}
__device__ __forceinline__ void fmix_hi(float& acc, unsigned w, float a){
    asm("v_fma_mix_f32 %0, %1, %2, %0 op_sel:[1,0,0] op_sel_hi:[1,0,0]"
        : "+v"(acc) : "v"(w), "v"(a));
}
__device__ __forceinline__ void mac8(float* acc, uint4 w, float a){
    fmix_lo(acc[0], w.x, a); fmix_hi(acc[1], w.x, a);
    fmix_lo(acc[2], w.y, a); fmix_hi(acc[3], w.y, a);
    fmix_lo(acc[4], w.z, a); fmix_hi(acc[5], w.z, a);
    fmix_lo(acc[6], w.w, a); fmix_hi(acc[7], w.w, a);
}
__device__ __forceinline__ void mac4(float4& acc, uint2 w, float a){
    fmix_lo(acc.x, w.x, a); fmix_hi(acc.y, w.x, a);
    fmix_lo(acc.z, w.y, a); fmix_hi(acc.w, w.y, a);
}

// ---------------- CSR build + weight prep ----------------
#define EB 1563   // ceil(400000/256)
#define TB 232    // ceil(59392/256)
__global__ void count_deg_tw_k(const int* __restrict__ dst, int* __restrict__ deg,
                               const float* __restrict__ W1, u16* __restrict__ W1t,
                               const float* __restrict__ W2, u16* __restrict__ W2t,
                               const float* __restrict__ Wm1, u16* __restrict__ W1mt,
                               const float* __restrict__ Wm2, u16* __restrict__ W2mt){
    if (blockIdx.x < EB){
        int e = blockIdx.x * 256 + threadIdx.x;
        if (e < NEDGES) atomicAdd(&deg[dst[e]], 1);
    } else {
        int i = (blockIdx.x - EB) * 256 + threadIdx.x;   // < 59392
        if (i < 32768){
            int n = i >> 7, k = i & 127;
            W1t[i] = f2bf(W1[k * 256 + n]);
        } else if (i < 49152){
            int ii = i - 32768;
            int n = ii >> 8, k = ii & 255;
            W2t[ii] = f2bf(W2[k * 64 + n]);
        } else if (i < 57344){
            int ii = i - 49152;
            int hd = ii >> 6, e = ii & 63;
            W1mt[ii] = f2bf(Wm1[e * 128 + hd]);
        } else if (i < 59392){
            int ii = i - 57344;
            int k = ii >> 7, hd = ii & 127;
            W2mt[ii] = f2bf(Wm2[hd * NK + k]);
        }
    }
}

__global__ void blocksum_k(const int* __restrict__ deg, int* __restrict__ bsum){
    __shared__ int sm[4];
    int i = blockIdx.x * 256 + threadIdx.x;
    int v = (i < NNODES) ? deg[i] : 0;
    for (int off = 1; off < 64; off <<= 1) v += __shfl_xor(v, off);
    int lane = threadIdx.x & 63, wid = threadIdx.x >> 6;
    if (lane == 0) sm[wid] = v;
    __syncthreads();
    if (threadIdx.x == 0) bsum[blockIdx.x] = sm[0] + sm[1] + sm[2] + sm[3];
}

__global__ void scan_write_k(const int* __restrict__ deg, const int* __restrict__ bsum,
                             int* __restrict__ rowptr){
    __shared__ int sm[4];
    __shared__ int sadd;
    int tid = threadIdx.x;
    int pv = (tid < blockIdx.x) ? bsum[tid] : 0;   // NB=196 < 256
    for (int off = 1; off < 64; off <<= 1) pv += __shfl_xor(pv, off);
    int lane = tid & 63, wid = tid >> 6;
    if (lane == 0) sm[wid] = pv;
    __syncthreads();
    if (tid == 0) sadd = sm[0] + sm[1] + sm[2] + sm[3];
    __syncthreads();

    int i = blockIdx.x * 256 + tid;
    int v = (i < NNODES) ? deg[i] : 0;
    int sv = v;
    for (int off = 1; off < 64; off <<= 1){ int t = __shfl_up(sv, off); if (lane >= off) sv += t; }
    __shared__ int wsum[4];
    if (lane == 63) wsum[wid] = sv;
    __syncthreads();
    int add = sadd;
    for (int w = 0; w < wid; w++) add += wsum[w];
    sv += add;
    if (i < NNODES) rowptr[i + 1] = sv;
    if (i == 0) rowptr[0] = 0;
}

__global__ void fill_csr_k(const int* __restrict__ src, const int* __restrict__ dst,
                           const int* __restrict__ rowptr, int* __restrict__ fillc,
                           int* __restrict__ col){
    int e = blockIdx.x * 256 + threadIdx.x;
    if (e < NEDGES){
        int d = dst[e];
        int pos = atomicAdd(&fillc[d], 1);
        col[rowptr[d] + pos] = src[e];
    }
}

// ---------------- L1: h1bh[8][N][32] = f16(x @ W1) head-major, fused att1 ------------
__global__ __launch_bounds__(256, 4) void l1_k(const float* __restrict__ x, const u16* __restrict__ W1t,
                     const float* __restrict__ att_s, const float* __restrict__ att_d,
                     u16* __restrict__ h1bh, float* __restrict__ as1h, float* __restrict__ ad1h){
    __shared__ u16 Bs[16384];   // 32 KB
    int tid = threadIdx.x;
    int lane = tid & 63, wid = tid >> 6;
    int ln = lane & 15, quad = lane >> 4;
    int m0 = blockIdx.x * 64 + wid * 16;
    int nb = blockIdx.y * 128;            // col base: 0 or 128
    int hb = blockIdx.y * 4;              // head base: 0 or 4
    int arow = m0 + ln; if (arow >= NNODES) arow = NNODES - 1;

    // stage W1t[nb..nb+128) into LDS (fragment order); 8 independent 16B loads/thread
#pragma unroll
    for (int it = 0; it < 8; it++){
        int p = it * 256 + tid;          // 0..2047
        int c = p >> 6, l = p & 63;
        int snt = c & 7, skt = c >> 3;
        int sln = l & 15, sq = l >> 4;
        uint4 v = *(const uint4*)(W1t + (size_t)(nb + snt * 16 + sln) * INC + skt * 32 + sq * 8);
        *(uint4*)(&Bs[p * 8]) = v;
    }

    // A-frag load+convert overlaps staging latency (before the barrier)
    bf16x8 a[4];
#pragma unroll
    for (int kt = 0; kt < 4; kt++){
        const float* ap = x + (size_t)arow * INC + kt * 32 + quad * 8;
        float4 v0 = *(const float4*)ap;
        float4 v1 = *(const float4*)(ap + 4);
        bf16x8 t;
        t[0] = f2bf_s(v0.x); t[1] = f2bf_s(v0.y); t[2] = f2bf_s(v0.z); t[3] = f2bf_s(v0.w);
        t[4] = f2bf_s(v1.x); t[5] = f2bf_s(v1.y); t[6] = f2bf_s(v1.z); t[7] = f2bf_s(v1.w);
        a[kt] = t;
    }

    __syncthreads();

    f32x4 acc[8];
#pragma unroll
    for (int nt = 0; nt < 8; nt++) acc[nt] = (f32x4){0.f, 0.f, 0.f, 0.f};

#pragma unroll
    for (int kt = 0; kt < 4; kt++){
#pragma unroll
        for (int nt = 0; nt < 8; nt++){
            bf16x8 b = *(const bf16x8*)(&Bs[(kt * 8 + nt) * 512 + lane * 8]);
            acc[nt] = __builtin_amdgcn_mfma_f32_16x16x32_bf16(a[kt], b, acc[nt], 0, 0, 0);
        }
    }

    // h1b write: head-major [h][N][32] f16
#pragma unroll
    for (int i = 0; i < 4; i++){
        int r = m0 + quad * 4 + i;
        if (r < NNODES){
#pragma unroll
            for (int nt = 0; nt < 8; nt++){
                int c  = nb + nt * 16 + ln;      // global channel
                int hh = c >> 5, c5 = c & 31;
                h1bh[((size_t)hh * NNODES + r) * 32 + c5] = f2h(acc[nt][i]);
            }
        }
    }

#pragma unroll
    for (int i = 0; i < 4; i++){
        int r = m0 + quad * 4 + i;
        float ps_keep = 0.f, pd_keep = 0.f;
#pragma unroll
        for (int h = 0; h < 4; h++){
            float ps = acc[2 * h][i]     * att_s[nb + h * 32 + ln]
                     + acc[2 * h + 1][i] * att_s[nb + h * 32 + 16 + ln];
            float pd = acc[2 * h][i]     * att_d[nb + h * 32 + ln]
                     + acc[2 * h + 1][i] * att_d[nb + h * 32 + 16 + ln];
            ps += __shfl_xor(ps, 1); pd += __shfl_xor(pd, 1);
            ps += __shfl_xor(ps, 2); pd += __shfl_xor(pd, 2);
            ps += __shfl_xor(ps, 4); pd += __shfl_xor(pd, 4);
            ps += __shfl_xor(ps, 8); pd += __shfl_xor(pd, 8);
            if (ln == h){ ps_keep = ps; pd_keep = pd; }
        }
        if (ln < 4 && r < NNODES){
            as1h[(size_t)(hb + ln) * NNODES + r] = ps_keep;
            ad1h[(size_t)(hb + ln) * NNODES + r] = pd_keep;
        }
    }
}

// ---------------- L2: h2bs[8][N][8] = f16(hL1b @ W2) slice-major, fused att2 ---------
// hL1b is head-major [8][N][32] bf16: A-frag for k-tile kt = head kt.
__global__ __launch_bounds__(256, 4) void l2_k(const u16* __restrict__ hL1b, const u16* __restrict__ W2t,
                     const float* __restrict__ att_s, const float* __restrict__ att_d,
                     u16* __restrict__ h2bs, float* __restrict__ as2, float* __restrict__ ad2){
    __shared__ u16 Bs[16384];   // 32 KB: chunk c=(kt*4+nt), kt in [0,8), nt in [0,4)
    int tid = threadIdx.x;
    int lane = tid & 63, wid = tid >> 6;
    int ln = lane & 15, quad = lane >> 4;
    int m0 = blockIdx.x * 64 + wid * 16;
    int arow = m0 + ln; if (arow >= NNODES) arow = NNODES - 1;

#pragma unroll
    for (int it = 0; it < 8; it++){
        int p = it * 256 + tid;          // 0..2047
        int c = p >> 6, l = p & 63;
        int snt = c & 3, skt = c >> 2;
        int sln = l & 15, sq = l >> 4;
        uint4 v = *(const uint4*)(W2t + (size_t)(snt * 16 + sln) * HC1 + skt * 32 + sq * 8);
        *(uint4*)(&Bs[p * 8]) = v;
    }

    __syncthreads();

    f32x4 acc[4];
#pragma unroll
    for (int nt = 0; nt < 4; nt++) acc[nt] = (f32x4){0.f, 0.f, 0.f, 0.f};

#pragma unroll
    for (int kt = 0; kt < 8; kt++){
        bf16x8 a = *(const bf16x8*)(hL1b + ((size_t)kt * NNODES + arow) * 32 + quad * 8);
#pragma unroll
        for (int nt = 0; nt < 4; nt++){
            bf16x8 b = *(const bf16x8*)(&Bs[(kt * 4 + nt) * 512 + lane * 8]);
            acc[nt] = __builtin_amdgcn_mfma_f32_16x16x32_bf16(a, b, acc[nt], 0, 0, 0);
        }
    }

#pragma unroll
    for (int i = 0; i < 4; i++){
        int r = m0 + quad * 4 + i;
        if (r < NNODES){
#pragma unroll
            for (int nt = 0; nt < 4; nt++){
                int c  = nt * 16 + ln;           // global channel
                int sl = c >> 3, pos = c & 7;    // slice-major [8][N][8]
                h2bs[((size_t)sl * NNODES + r) * 8 + pos] = f2h(acc[nt][i]);
            }
        }
        float ps = acc[0][i] * att_s[ln]      + acc[1][i] * att_s[16 + ln]
                 + acc[2][i] * att_s[32 + ln] + acc[3][i] * att_s[48 + ln];
        float pd = acc[0][i] * att_d[ln]      + acc[1][i] * att_d[16 + ln]
                 + acc[2][i] * att_d[32 + ln] + acc[3][i] * att_d[48 + ln];
        ps += __shfl_xor(ps, 1); pd += __shfl_xor(pd, 1);
        ps += __shfl_xor(ps, 2); pd += __shfl_xor(pd, 2);
        ps += __shfl_xor(ps, 4); pd += __shfl_xor(pd, 4);
        ps += __shfl_xor(ps, 8); pd += __shfl_xor(pd, 8);
        if (ln == 0 && r < NNODES){ as2[r] = ps; ad2[r] = pd; }
    }
}

// ---------------- GAT layer 1 aggregation: head-partitioned, no-max softmax, --------
// late normalization (R7 version — best measured: 45.7us). 8-lane group per (dst,head).
__global__ void gat1_agg_k(const u16* __restrict__ h1bh, const float* __restrict__ as1h,
                           const float* __restrict__ ad1h, const int* __restrict__ rowptr,
                           const int* __restrict__ col, const float* __restrict__ b1,
                           u16* __restrict__ outb){
    int lane = threadIdx.x & 63, wid = threadIdx.x >> 6;
    int g = lane >> 3, t = lane & 7;
    int h = blockIdx.x & 7;
    int d = (blockIdx.x >> 3) * 32 + wid * 8 + g;
    bool valid = (d < NNODES);
    int dd = valid ? d : (NNODES - 1);
    int row0 = rowptr[dd];
    int deg  = rowptr[dd + 1] - row0;

    const float* ash = as1h + (size_t)h * NNODES;
    float adst = ad1h[(size_t)h * NNODES + dd];
    const u16* hb = h1bh + (size_t)h * NNODES * 32;

    // col loads (round 1), then score gathers + self row (round 2, concurrent)
    int sv0 = (t < deg)     ? col[row0 + t]     : dd;
    int sv1 = (8 + t < deg) ? col[row0 + 8 + t] : dd;
    uint2 wself = *(const uint2*)(hb + (size_t)dd * 32 + t * 4);
    float ev0 = ash[sv0];
    float ev1 = ash[sv1];

    float a_self = __expf(lrelu(ash[dd] + adst));
    float x0 = (t < deg)     ? __expf(lrelu(ev0 + adst)) : 0.f;
    float x1 = (8 + t < deg) ? __expf(lrelu(ev1 + adst)) : 0.f;

    float4 acc = make_float4(0.f, 0.f, 0.f, 0.f);
    mac4(acc, wself, a_self);

    int gb = g * 8;
    if (deg > 0){
        int s_arr[4]; float a_arr[4]; uint2 w_arr[4];
#pragma unroll
        for (int j = 0; j < 4; j++){ s_arr[j] = __shfl(sv0, gb + j); a_arr[j] = __shfl(x0, gb + j); }
#pragma unroll
        for (int j = 0; j < 4; j++) w_arr[j] = *(const uint2*)(hb + (size_t)s_arr[j] * 32 + t * 4);
#pragma unroll
        for (int j = 0; j < 4; j++) mac4(acc, w_arr[j], a_arr[j]);
        if (deg > 4){
#pragma unroll
            for (int j = 0; j < 4; j++){ s_arr[j] = __shfl(sv0, gb + 4 + j); a_arr[j] = __shfl(x0, gb + 4 + j); }
#pragma unroll
            for (int j = 0; j < 4; j++) w_arr[j] = *(const uint2*)(hb + (size_t)s_arr[j] * 32 + t * 4);
#pragma unroll
            for (int j = 0; j < 4; j++) mac4(acc, w_arr[j], a_arr[j]);
        }
    }
    if (deg > 8){
        int s_arr[4]; float a_arr[4]; uint2 w_arr[4];
#pragma unroll
        for (int j = 0; j < 4; j++){ s_arr[j] = __shfl(sv1, gb + j); a_arr[j] = __shfl(x1, gb + j); }
#pragma unroll
        for (int j = 0; j < 4; j++) w_arr[j] = *(const uint2*)(hb + (size_t)s_arr[j] * 32 + t * 4);
#pragma unroll
        for (int j = 0; j < 4; j++) mac4(acc, w_arr[j], a_arr[j]);
        if (deg > 12){
#pragma unroll
            for (int j = 0; j < 4; j++){ s_arr[j] = __shfl(sv1, gb + 4 + j); a_arr[j] = __shfl(x1, gb + 4 + j); }
#pragma unroll
            for (int j = 0; j < 4; j++) w_arr[j] = *(const uint2*)(hb + (size_t)s_arr[j] * 32 + t * 4);
#pragma unroll
            for (int j = 0; j < 4; j++) mac4(acc, w_arr[j], a_arr[j]);
        }
    }
    float tsum = 0.f;
    if (deg > 16){
        for (int idx = 16; idx < deg; idx++){
            int s = col[row0 + idx];   // group-uniform
            float a = __expf(lrelu(ash[s] + adst));
            tsum += a;                 // uniform across the 8-lane group
            uint2 w = *(const uint2*)(hb + (size_t)s * 32 + t * 4);
            mac4(acc, w, a);
        }
    }

    // vsum reduction AFTER the MACs (off the critical path)
    float part = x0 + x1;
    part += __shfl_xor(part, 1);
    part += __shfl_xor(part, 2);
    part += __shfl_xor(part, 4);
    float rden = 1.f / (part + a_self + tsum + EPS_F);

    if (valid){
        float4 bb = *(const float4*)(b1 + h * 32 + t * 4);
        uint2 o;
        o.x = (unsigned)f2bf(eluf(acc.x * rden + bb.x)) | ((unsigned)f2bf(eluf(acc.y * rden + bb.y)) << 16);
        o.y = (unsigned)f2bf(eluf(acc.z * rden + bb.z)) | ((unsigned)f2bf(eluf(acc.w * rden + bb.w)) << 16);
        *(uint2*)(outb + ((size_t)h * NNODES + d) * 32 + t * 4) = o;
    }
}

// ---------------- GAT layer 2 aggregation: 8-way channel-slice split --------------
// slice s = blockIdx&7 -> XCD; per-slice table = 50000*8ch*2B = 800KB (L2-resident).
// 16-lane group per (dst,slice); LANE-PER-EDGE: alpha is lane-local (no shuffles
// before MACs); one gather round; unified tail for any degree.
__global__ void gat2_agg_k(const u16* __restrict__ h2bs, const float* __restrict__ as2,
                           const float* __restrict__ ad2, const int* __restrict__ rowptr,
                           const int* __restrict__ col, const float* __restrict__ b2,
                           float* __restrict__ emb){
    int lane = threadIdx.x & 63, wid = threadIdx.x >> 6;
    int l16 = lane & 15;
    int grp = (lane >> 4) & 3;
    int s = blockIdx.x & 7;                              // channel slice -> XCD
    int d = (blockIdx.x >> 3) * 16 + wid * 4 + grp;      // 3125*16 = 50000 exact

    int row0 = rowptr[d];
    int deg  = rowptr[d + 1] - row0;

    float adst = ad2[d];
    float a_self = __expf(lrelu(as2[d] + adst));
    const u16* hs = h2bs + (size_t)s * NNODES * 8;

    // round 1: edge indices; round 2: score gather + row-slice gather (concurrent)
    int sv = (l16 < deg) ? col[row0 + l16] : d;
    float er = as2[sv];
    uint4 w = *(const uint4*)(hs + (size_t)sv * 8);      // 8 f16 channels
    float x = (l16 < deg) ? __expf(lrelu(er + adst)) : 0.f;

    float acc[8] = {0.f, 0.f, 0.f, 0.f, 0.f, 0.f, 0.f, 0.f};
    mac8(acc, w, x);
    if (l16 == 0){
        uint4 ws = *(const uint4*)(hs + (size_t)d * 8);
        mac8(acc, ws, a_self);
    }
    float xsum = x;
    // unified tail (deg > 16): lane-strided, alpha stays lane-local
    for (int idx = 16 + l16; idx < deg; idx += 16){
        int cj = col[row0 + idx];
        float a = __expf(lrelu(as2[cj] + adst));
        uint4 wt = *(const uint4*)(hs + (size_t)cj * 8);
        mac8(acc, wt, a);
        xsum += a;
    }

    // reduce over the 16-lane group (after MACs)
#pragma unroll
    for (int k = 0; k < 8; k++){
        acc[k] += __shfl_xor(acc[k], 1);
        acc[k] += __shfl_xor(acc[k], 2);
        acc[k] += __shfl_xor(acc[k], 4);
        acc[k] += __shfl_xor(acc[k], 8);
    }
    xsum += __shfl_xor(xsum, 1);
    xsum += __shfl_xor(xsum, 2);
    xsum += __shfl_xor(xsum, 4);
    xsum += __shfl_xor(xsum, 8);
    float rden = 1.f / (xsum + a_self + EPS_F);

    if (l16 == 0){
        const float* bp = b2 + s * 8;
        float4 o0 = make_float4(acc[0] * rden + bp[0], acc[1] * rden + bp[1],
                                acc[2] * rden + bp[2], acc[3] * rden + bp[3]);
        float4 o1 = make_float4(acc[4] * rden + bp[4], acc[5] * rden + bp[5],
                                acc[6] * rden + bp[6], acc[7] * rden + bp[7]);
        float* op = emb + (size_t)d * OUTC + s * 8;
        *(float4*)op = o0;
        *(float4*)(op + 4) = o1;
    }
}

// ---------------- MLP head + softmax via MFMA ----------------
__global__ void mlp_mfma_k(const float* __restrict__ emb, const u16* __restrict__ W1mt,
                           const float* __restrict__ bm1, const u16* __restrict__ W2mt,
                           const float* __restrict__ bm2, float* __restrict__ sout){
    __shared__ u16 hid[4][16][136];
    int lane = threadIdx.x & 63, wid = threadIdx.x >> 6;
    int ln = lane & 15, quad = lane >> 4;
    int m0 = blockIdx.x * 64 + wid * 16;
    int arow = m0 + ln; if (arow >= NNODES) arow = NNODES - 1;

    bf16x8 a[2];
#pragma unroll
    for (int kt = 0; kt < 2; kt++){
        const float* ap = emb + (size_t)arow * OUTC + kt * 32 + quad * 8;
        float4 v0 = *(const float4*)ap;
        float4 v1 = *(const float4*)(ap + 4);
        bf16x8 t;
        t[0] = f2bf_s(v0.x); t[1] = f2bf_s(v0.y); t[2] = f2bf_s(v0.z); t[3] = f2bf_s(v0.w);
        t[4] = f2bf_s(v1.x); t[5] = f2bf_s(v1.y); t[6] = f2bf_s(v1.z); t[7] = f2bf_s(v1.w);
        a[kt] = t;
    }

    f32x4 acc[8];
#pragma unroll
    for (int nt = 0; nt < 8; nt++) acc[nt] = (f32x4){0.f, 0.f, 0.f, 0.f};
#pragma unroll
    for (int kt = 0; kt < 2; kt++){
#pragma unroll
        for (int nt = 0; nt < 8; nt++){
            bf16x8 b = *(const bf16x8*)(W1mt + (size_t)(nt * 16 + ln) * OUTC + kt * 32 + quad * 8);
            acc[nt] = __builtin_amdgcn_mfma_f32_16x16x32_bf16(a[kt], b, acc[nt], 0, 0, 0);
        }
    }

#pragma unroll
    for (int nt = 0; nt < 8; nt++){
        float bb = bm1[nt * 16 + ln];
#pragma unroll
        for (int i = 0; i < 4; i++){
            float h = fmaxf(acc[nt][i] + bb, 0.f);
            hid[wid][quad * 4 + i][nt * 16 + ln] = f2bf(h);
        }
    }

    f32x4 acc2 = (f32x4){0.f, 0.f, 0.f, 0.f};
#pragma unroll
    for (int kt = 0; kt < 4; kt++){
        bf16x8 ah = *(const bf16x8*)&hid[wid][ln][kt * 32 + quad * 8];
        bf16x8 bw = *(const bf16x8*)(W2mt + (size_t)ln * 128 + kt * 32 + quad * 8);
        acc2 = __builtin_amdgcn_mfma_f32_16x16x32_bf16(ah, bw, acc2, 0, 0, 0);
    }

    float bcl = bm2[ln];
#pragma unroll
    for (int i = 0; i < 4; i++){
        int r = m0 + quad * 4 + i;
        float lg = acc2[i] + bcl;
        float m = lg;
        m = fmaxf(m, __shfl_xor(m, 1));
        m = fmaxf(m, __shfl_xor(m, 2));
        m = fmaxf(m, __shfl_xor(m, 4));
        m = fmaxf(m, __shfl_xor(m, 8));
        float ex = __expf(lg - m);
        float s = ex;
        s += __shfl_xor(s, 1);
        s += __shfl_xor(s, 2);
        s += __shfl_xor(s, 4);
        s += __shfl_xor(s, 8);
        if (r < NNODES) sout[(size_t)r * NK + ln] = ex / s;
    }
}

// ---------------- launcher ----------------
extern "C" void kernel_launch(void* const* d_in, const int* in_sizes, int n_in,
                              void* d_out, int out_size, void* d_ws, size_t ws_size,
                              hipStream_t stream){
    const float* x      = (const float*)d_in[0];
    const int*   ei     = (const int*)d_in[1];
    const int*   srcv   = ei;
    const int*   dstv   = ei + NEDGES;
    const float* W1     = (const float*)d_in[2];
    const float* att_s1 = (const float*)d_in[3];
    const float* att_d1 = (const float*)d_in[4];
    const float* b1     = (const float*)d_in[5];
    const float* W2     = (const float*)d_in[6];
    const float* att_s2 = (const float*)d_in[7];
    const float* att_d2 = (const float*)d_in[8];
    const float* b2     = (const float*)d_in[9];
    const float* Wm1    = (const float*)d_in[10];
    const float* bm1    = (const float*)d_in[11];
    const float* Wm2    = (const float*)d_in[12];
    const float* bm2    = (const float*)d_in[13];

    float* out     = (float*)d_out;                     // s: [N,16]
    float* emb_out = out + (size_t)NNODES * NK;         // embeddings: [N,64]

    u16* h1b   = (u16*)d_ws;                            // [8][N][32] f16
    u16* hL1b  = h1b  + (size_t)NNODES * HC1;           // [8][N][32] bf16
    u16* h2b   = hL1b + (size_t)NNODES * HC1;           // [8][N][8] f16 (slice-major)
    u16* W1t   = h2b  + (size_t)NNODES * OUTC;          // 256*128
    u16* W2t   = W1t + 256 * 128;                       // 64*256
    u16* W1mt  = W2t + 64 * 256;                        // 128*64
    u16* W2mt  = W1mt + 128 * 64;                       // 16*128
    float* as1 = (float*)(W2mt + 16 * 128);             // [8][N]
    float* ad1 = as1 + (size_t)NNODES * NHEADS;         // [8][N]
    float* as2 = ad1 + (size_t)NNODES * NHEADS;         // N
    float* ad2 = as2 + NNODES;                          // N
    int* deg    = (int*)(ad2 + NNODES);                 // N   (deg+fillc adjacent -> 1 memset)
    int* fillc  = deg + NNODES;                         // N
    int* rowptr = fillc + NNODES;                       // N+1
    int* bsum   = rowptr + NNODES + 1;                  // 256
    int* colv   = bsum + 256;                           // E

    hipMemsetAsync(deg, 0, 2 * NNODES * sizeof(int), stream);

    const int NB = (NNODES + 255) / 256;   // 196

    count_deg_tw_k<<<EB + TB, 256, 0, stream>>>(dstv, deg, W1, W1t, W2, W2t, Wm1, W1mt, Wm2, W2mt);
    blocksum_k<<<NB, 256, 0, stream>>>(deg, bsum);
    scan_write_k<<<NB, 256, 0, stream>>>(deg, bsum, rowptr);
    fill_csr_k<<<(NEDGES + 255) / 256, 256, 0, stream>>>(srcv, dstv, rowptr, fillc, colv);

    const int MB = (NNODES + 63) / 64;   // 782

    l1_k<<<dim3(MB, 2), 256, 0, stream>>>(x, W1t, att_s1, att_d1, h1b, as1, ad1);
    // head-partitioned: 8 heads x ceil(N/32) node-chunks; head = blockIdx & 7 -> XCD id
    gat1_agg_k<<<8 * ((NNODES + 31) / 32), 256, 0, stream>>>(h1b, as1, ad1, rowptr, colv, b1, hL1b);

    l2_k<<<MB, 256, 0, stream>>>(hL1b, W2t, att_s2, att_d2, h2b, as2, ad2);
    // slice-partitioned: 8 slices x (N/16) node-chunks; slice = blockIdx & 7 -> XCD id
    gat2_agg_k<<<8 * (NNODES / 16), 256, 0, stream>>>(h2b, as2, ad2, rowptr, colv, b2, emb_out);

    mlp_mfma_k<<<MB, 256, 0, stream>>>(emb_out, W1mt, bm1, W2mt, bm2, out);
}

// Round 10
// 248.577 us; speedup vs baseline: 1.0991x; 1.0991x over previous
//
#include <hip/hip_runtime.h>
#include <hip/hip_fp16.h>
#include <math.h>

#define NNODES 50000
#define NEDGES 400000
#define INC    128
#define HC1    256   // HEADS*HID
#define NHEADS 8
#define OUTC   64
#define NK     16
#define NEG_SLOPE 0.2f
#define EPS_F  1e-16f

typedef unsigned short u16;
typedef __attribute__((ext_vector_type(8))) short bf16x8;
typedef __attribute__((ext_vector_type(4))) float f32x4;

__device__ __forceinline__ float lrelu(float x){ return x > 0.f ? x : NEG_SLOPE * x; }
__device__ __forceinline__ float eluf(float x){ return x > 0.f ? x : (__expf(x) - 1.f); }
__device__ __forceinline__ float bf2f(u16 v){ return __uint_as_float((unsigned)v << 16); }
__device__ __forceinline__ u16 f2bf(float f){
    unsigned u = __float_as_uint(f);
    unsigned r = (u + 0x7FFFu + ((u >> 16) & 1u)) >> 16;   // RTNE
    return (u16)r;
}
__device__ __forceinline__ short f2bf_s(float f){ return (short)f2bf(f); }
__device__ __forceinline__ u16 f2h(float f){ return __half_as_ushort(__float2half(f)); }
__device__ __forceinline__ float h2f(u16 v){ return __half2float(__ushort_as_half(v)); }

// one-instruction f16*f32+f32 MAC (no unpack)
__device__ __forceinline__ void fmix_lo(float& acc, unsigned w, float a){
    asm("v_fma_mix_f32 %0, %1, %2, %0 op_sel:[0,0,0] op_sel_hi:[1,0,0]"
        : "+v"(acc) : "v"(w), "v"(a));
}
__device__ __forceinline__ void fmix_hi(float& acc, unsigned w, float a){
    asm("v_fma_mix_f32 %0, %1, %2, %0 op_sel:[1,0,0] op_sel_hi:[1,0,0]"
        : "+v"(acc) : "v"(w), "v"(a));
}
__device__ __forceinline__ void mac8(float* acc, uint4 w, float a){
    fmix_lo(acc[0], w.x, a); fmix_hi(acc[1], w.x, a);
    fmix_lo(acc[2], w.y, a); fmix_hi(acc[3], w.y, a);
    fmix_lo(acc[4], w.z, a); fmix_hi(acc[5], w.z, a);
    fmix_lo(acc[6], w.w, a); fmix_hi(acc[7], w.w, a);
}
__device__ __forceinline__ void mac4(float4& acc, uint2 w, float a){
    fmix_lo(acc.x, w.x, a); fmix_hi(acc.y, w.x, a);
    fmix_lo(acc.z, w.y, a); fmix_hi(acc.w, w.y, a);
}

// ---------------- CSR build + weight prep ----------------
#define EB 1563   // ceil(400000/256)
#define TB 232    // ceil(59392/256)
#define MBD 782   // ceil(50000/64)
__global__ void count_deg_tw_k(const int* __restrict__ dst, int* __restrict__ deg,
                               const float* __restrict__ W1, u16* __restrict__ W1t,
                               const float* __restrict__ W2, u16* __restrict__ W2t,
                               const float* __restrict__ Wm1, u16* __restrict__ W1mt,
                               const float* __restrict__ Wm2, u16* __restrict__ W2mt){
    if (blockIdx.x < EB){
        int e = blockIdx.x * 256 + threadIdx.x;
        if (e < NEDGES) atomicAdd(&deg[dst[e]], 1);
    } else {
        int i = (blockIdx.x - EB) * 256 + threadIdx.x;   // < 59392
        if (i < 32768){
            int n = i >> 7, k = i & 127;
            W1t[i] = f2bf(W1[k * 256 + n]);
        } else if (i < 49152){
            int ii = i - 32768;
            int n = ii >> 8, k = ii & 255;
            W2t[ii] = f2bf(W2[k * 64 + n]);
        } else if (i < 57344){
            int ii = i - 49152;
            int hd = ii >> 6, e = ii & 63;
            W1mt[ii] = f2bf(Wm1[e * 128 + hd]);
        } else if (i < 59392){
            int ii = i - 57344;
            int k = ii >> 7, hd = ii & 127;
            W2mt[ii] = f2bf(Wm2[hd * NK + k]);
        }
    }
}

__global__ void blocksum_k(const int* __restrict__ deg, int* __restrict__ bsum){
    __shared__ int sm[4];
    int i = blockIdx.x * 256 + threadIdx.x;
    int v = (i < NNODES) ? deg[i] : 0;
    for (int off = 1; off < 64; off <<= 1) v += __shfl_xor(v, off);
    int lane = threadIdx.x & 63, wid = threadIdx.x >> 6;
    if (lane == 0) sm[wid] = v;
    __syncthreads();
    if (threadIdx.x == 0) bsum[blockIdx.x] = sm[0] + sm[1] + sm[2] + sm[3];
}

__global__ void scan_write_k(const int* __restrict__ deg, const int* __restrict__ bsum,
                             int* __restrict__ rowptr){
    __shared__ int sm[4];
    __shared__ int sadd;
    int tid = threadIdx.x;
    int pv = (tid < blockIdx.x) ? bsum[tid] : 0;   // NB=196 < 256
    for (int off = 1; off < 64; off <<= 1) pv += __shfl_xor(pv, off);
    int lane = tid & 63, wid = tid >> 6;
    if (lane == 0) sm[wid] = pv;
    __syncthreads();
    if (tid == 0) sadd = sm[0] + sm[1] + sm[2] + sm[3];
    __syncthreads();

    int i = blockIdx.x * 256 + tid;
    int v = (i < NNODES) ? deg[i] : 0;
    int sv = v;
    for (int off = 1; off < 64; off <<= 1){ int t = __shfl_up(sv, off); if (lane >= off) sv += t; }
    __shared__ int wsum[4];
    if (lane == 63) wsum[wid] = sv;
    __syncthreads();
    int add = sadd;
    for (int w = 0; w < wid; w++) add += wsum[w];
    sv += add;
    if (i < NNODES) rowptr[i + 1] = sv;
    if (i == 0) rowptr[0] = 0;
}

// ---------------- FUSED: fill_csr (blocks 0..EB-1) + L1 (blocks EB..EB+2*MBD-1) -----
// fill_csr depends on rowptr (prior dispatch); l1 depends only on x/W1t — independent,
// so the atomic/scatter fill work overlaps l1's MFMA/LDS work in one dispatch.
// L1: h1bh[8][N][32] = f16(x @ W1) head-major, fused att1.
__global__ __launch_bounds__(256, 4) void fill_l1_k(
        const int* __restrict__ src, const int* __restrict__ dstv,
        const int* __restrict__ rowptr, int* __restrict__ fillc, int* __restrict__ col,
        const float* __restrict__ x, const u16* __restrict__ W1t,
        const float* __restrict__ att_s, const float* __restrict__ att_d,
        u16* __restrict__ h1bh, float* __restrict__ as1h, float* __restrict__ ad1h){
    __shared__ u16 Bs[16384];   // 32 KB (l1 branch only)
    if (blockIdx.x < EB){
        int e = blockIdx.x * 256 + threadIdx.x;
        if (e < NEDGES){
            int d = dstv[e];
            int pos = atomicAdd(&fillc[d], 1);
            col[rowptr[d] + pos] = src[e];
        }
        return;
    }
    int li = blockIdx.x - EB;             // 0..2*MBD-1
    int by = (li >= MBD) ? 1 : 0;
    int bx = li - by * MBD;

    int tid = threadIdx.x;
    int lane = tid & 63, wid = tid >> 6;
    int ln = lane & 15, quad = lane >> 4;
    int m0 = bx * 64 + wid * 16;
    int nb = by * 128;            // col base: 0 or 128
    int hb = by * 4;              // head base: 0 or 4
    int arow = m0 + ln; if (arow >= NNODES) arow = NNODES - 1;

    // stage W1t[nb..nb+128) into LDS (fragment order); 8 independent 16B loads/thread
#pragma unroll
    for (int it = 0; it < 8; it++){
        int p = it * 256 + tid;          // 0..2047
        int c = p >> 6, l = p & 63;
        int snt = c & 7, skt = c >> 3;
        int sln = l & 15, sq = l >> 4;
        uint4 v = *(const uint4*)(W1t + (size_t)(nb + snt * 16 + sln) * INC + skt * 32 + sq * 8);
        *(uint4*)(&Bs[p * 8]) = v;
    }

    // A-frag load+convert overlaps staging latency (before the barrier)
    bf16x8 a[4];
#pragma unroll
    for (int kt = 0; kt < 4; kt++){
        const float* ap = x + (size_t)arow * INC + kt * 32 + quad * 8;
        float4 v0 = *(const float4*)ap;
        float4 v1 = *(const float4*)(ap + 4);
        bf16x8 t;
        t[0] = f2bf_s(v0.x); t[1] = f2bf_s(v0.y); t[2] = f2bf_s(v0.z); t[3] = f2bf_s(v0.w);
        t[4] = f2bf_s(v1.x); t[5] = f2bf_s(v1.y); t[6] = f2bf_s(v1.z); t[7] = f2bf_s(v1.w);
        a[kt] = t;
    }

    __syncthreads();

    f32x4 acc[8];
#pragma unroll
    for (int nt = 0; nt < 8; nt++) acc[nt] = (f32x4){0.f, 0.f, 0.f, 0.f};

#pragma unroll
    for (int kt = 0; kt < 4; kt++){
#pragma unroll
        for (int nt = 0; nt < 8; nt++){
            bf16x8 b = *(const bf16x8*)(&Bs[(kt * 8 + nt) * 512 + lane * 8]);
            acc[nt] = __builtin_amdgcn_mfma_f32_16x16x32_bf16(a[kt], b, acc[nt], 0, 0, 0);
        }
    }

    // h1b write: head-major [h][N][32] f16
#pragma unroll
    for (int i = 0; i < 4; i++){
        int r = m0 + quad * 4 + i;
        if (r < NNODES){
#pragma unroll
            for (int nt = 0; nt < 8; nt++){
                int c  = nb + nt * 16 + ln;      // global channel
                int hh = c >> 5, c5 = c & 31;
                h1bh[((size_t)hh * NNODES + r) * 32 + c5] = f2h(acc[nt][i]);
            }
        }
    }

#pragma unroll
    for (int i = 0; i < 4; i++){
        int r = m0 + quad * 4 + i;
        float ps_keep = 0.f, pd_keep = 0.f;
#pragma unroll
        for (int h = 0; h < 4; h++){
            float ps = acc[2 * h][i]     * att_s[nb + h * 32 + ln]
                     + acc[2 * h + 1][i] * att_s[nb + h * 32 + 16 + ln];
            float pd = acc[2 * h][i]     * att_d[nb + h * 32 + ln]
                     + acc[2 * h + 1][i] * att_d[nb + h * 32 + 16 + ln];
            ps += __shfl_xor(ps, 1); pd += __shfl_xor(pd, 1);
            ps += __shfl_xor(ps, 2); pd += __shfl_xor(pd, 2);
            ps += __shfl_xor(ps, 4); pd += __shfl_xor(pd, 4);
            ps += __shfl_xor(ps, 8); pd += __shfl_xor(pd, 8);
            if (ln == h){ ps_keep = ps; pd_keep = pd; }
        }
        if (ln < 4 && r < NNODES){
            as1h[(size_t)(hb + ln) * NNODES + r] = ps_keep;
            ad1h[(size_t)(hb + ln) * NNODES + r] = pd_keep;
        }
    }
}

// ---------------- L2: h2b[N,64] = f16(hL1b @ W2), fused att2 (LDS-staged B) ----------
// hL1b is head-major [8][N][32] bf16: A-frag for k-tile kt = head kt.
__global__ __launch_bounds__(256, 4) void l2_k(const u16* __restrict__ hL1b, const u16* __restrict__ W2t,
                     const float* __restrict__ att_s, const float* __restrict__ att_d,
                     u16* __restrict__ h2b, float* __restrict__ as2, float* __restrict__ ad2){
    __shared__ u16 Bs[16384];   // 32 KB: chunk c=(kt*4+nt), kt in [0,8), nt in [0,4)
    int tid = threadIdx.x;
    int lane = tid & 63, wid = tid >> 6;
    int ln = lane & 15, quad = lane >> 4;
    int m0 = blockIdx.x * 64 + wid * 16;
    int arow = m0 + ln; if (arow >= NNODES) arow = NNODES - 1;

#pragma unroll
    for (int it = 0; it < 8; it++){
        int p = it * 256 + tid;          // 0..2047
        int c = p >> 6, l = p & 63;
        int snt = c & 3, skt = c >> 2;
        int sln = l & 15, sq = l >> 4;
        uint4 v = *(const uint4*)(W2t + (size_t)(snt * 16 + sln) * HC1 + skt * 32 + sq * 8);
        *(uint4*)(&Bs[p * 8]) = v;
    }

    __syncthreads();

    f32x4 acc[4];
#pragma unroll
    for (int nt = 0; nt < 4; nt++) acc[nt] = (f32x4){0.f, 0.f, 0.f, 0.f};

#pragma unroll
    for (int kt = 0; kt < 8; kt++){
        bf16x8 a = *(const bf16x8*)(hL1b + ((size_t)kt * NNODES + arow) * 32 + quad * 8);
#pragma unroll
        for (int nt = 0; nt < 4; nt++){
            bf16x8 b = *(const bf16x8*)(&Bs[(kt * 4 + nt) * 512 + lane * 8]);
            acc[nt] = __builtin_amdgcn_mfma_f32_16x16x32_bf16(a, b, acc[nt], 0, 0, 0);
        }
    }

#pragma unroll
    for (int i = 0; i < 4; i++){
        int r = m0 + quad * 4 + i;
        if (r < NNODES){
#pragma unroll
            for (int nt = 0; nt < 4; nt++)
                h2b[(size_t)r * OUTC + nt * 16 + ln] = f2h(acc[nt][i]);
        }
        float ps = acc[0][i] * att_s[ln]      + acc[1][i] * att_s[16 + ln]
                 + acc[2][i] * att_s[32 + ln] + acc[3][i] * att_s[48 + ln];
        float pd = acc[0][i] * att_d[ln]      + acc[1][i] * att_d[16 + ln]
                 + acc[2][i] * att_d[32 + ln] + acc[3][i] * att_d[48 + ln];
        ps += __shfl_xor(ps, 1); pd += __shfl_xor(pd, 1);
        ps += __shfl_xor(ps, 2); pd += __shfl_xor(pd, 2);
        ps += __shfl_xor(ps, 4); pd += __shfl_xor(pd, 4);
        ps += __shfl_xor(ps, 8); pd += __shfl_xor(pd, 8);
        if (ln == 0 && r < NNODES){ as2[r] = ps; ad2[r] = pd; }
    }
}

// ---------------- GAT layer 1 aggregation: head-partitioned, no-max softmax, --------
// late normalization (best measured: 45.7us). 8-lane group per (dst,head).
__global__ void gat1_agg_k(const u16* __restrict__ h1bh, const float* __restrict__ as1h,
                           const float* __restrict__ ad1h, const int* __restrict__ rowptr,
                           const int* __restrict__ col, const float* __restrict__ b1,
                           u16* __restrict__ outb){
    int lane = threadIdx.x & 63, wid = threadIdx.x >> 6;
    int g = lane >> 3, t = lane & 7;
    int h = blockIdx.x & 7;
    int d = (blockIdx.x >> 3) * 32 + wid * 8 + g;
    bool valid = (d < NNODES);
    int dd = valid ? d : (NNODES - 1);
    int row0 = rowptr[dd];
    int deg  = rowptr[dd + 1] - row0;

    const float* ash = as1h + (size_t)h * NNODES;
    float adst = ad1h[(size_t)h * NNODES + dd];
    const u16* hb = h1bh + (size_t)h * NNODES * 32;

    // col loads (round 1), then score gathers + self row (round 2, concurrent)
    int sv0 = (t < deg)     ? col[row0 + t]     : dd;
    int sv1 = (8 + t < deg) ? col[row0 + 8 + t] : dd;
    uint2 wself = *(const uint2*)(hb + (size_t)dd * 32 + t * 4);
    float ev0 = ash[sv0];
    float ev1 = ash[sv1];

    float a_self = __expf(lrelu(ash[dd] + adst));
    float x0 = (t < deg)     ? __expf(lrelu(ev0 + adst)) : 0.f;
    float x1 = (8 + t < deg) ? __expf(lrelu(ev1 + adst)) : 0.f;

    float4 acc = make_float4(0.f, 0.f, 0.f, 0.f);
    mac4(acc, wself, a_self);

    int gb = g * 8;
    if (deg > 0){
        int s_arr[4]; float a_arr[4]; uint2 w_arr[4];
#pragma unroll
        for (int j = 0; j < 4; j++){ s_arr[j] = __shfl(sv0, gb + j); a_arr[j] = __shfl(x0, gb + j); }
#pragma unroll
        for (int j = 0; j < 4; j++) w_arr[j] = *(const uint2*)(hb + (size_t)s_arr[j] * 32 + t * 4);
#pragma unroll
        for (int j = 0; j < 4; j++) mac4(acc, w_arr[j], a_arr[j]);
        if (deg > 4){
#pragma unroll
            for (int j = 0; j < 4; j++){ s_arr[j] = __shfl(sv0, gb + 4 + j); a_arr[j] = __shfl(x0, gb + 4 + j); }
#pragma unroll
            for (int j = 0; j < 4; j++) w_arr[j] = *(const uint2*)(hb + (size_t)s_arr[j] * 32 + t * 4);
#pragma unroll
            for (int j = 0; j < 4; j++) mac4(acc, w_arr[j], a_arr[j]);
        }
    }
    if (deg > 8){
        int s_arr[4]; float a_arr[4]; uint2 w_arr[4];
#pragma unroll
        for (int j = 0; j < 4; j++){ s_arr[j] = __shfl(sv1, gb + j); a_arr[j] = __shfl(x1, gb + j); }
#pragma unroll
        for (int j = 0; j < 4; j++) w_arr[j] = *(const uint2*)(hb + (size_t)s_arr[j] * 32 + t * 4);
#pragma unroll
        for (int j = 0; j < 4; j++) mac4(acc, w_arr[j], a_arr[j]);
        if (deg > 12){
#pragma unroll
            for (int j = 0; j < 4; j++){ s_arr[j] = __shfl(sv1, gb + 4 + j); a_arr[j] = __shfl(x1, gb + 4 + j); }
#pragma unroll
            for (int j = 0; j < 4; j++) w_arr[j] = *(const uint2*)(hb + (size_t)s_arr[j] * 32 + t * 4);
#pragma unroll
            for (int j = 0; j < 4; j++) mac4(acc, w_arr[j], a_arr[j]);
        }
    }
    float tsum = 0.f;
    if (deg > 16){
        for (int idx = 16; idx < deg; idx++){
            int s = col[row0 + idx];   // group-uniform
            float a = __expf(lrelu(ash[s] + adst));
            tsum += a;                 // uniform across the 8-lane group
            uint2 w = *(const uint2*)(hb + (size_t)s * 32 + t * 4);
            mac4(acc, w, a);
        }
    }

    // vsum reduction AFTER the MACs (off the critical path)
    float part = x0 + x1;
    part += __shfl_xor(part, 1);
    part += __shfl_xor(part, 2);
    part += __shfl_xor(part, 4);
    float rden = 1.f / (part + a_self + tsum + EPS_F);

    if (valid){
        float4 bb = *(const float4*)(b1 + h * 32 + t * 4);
        uint2 o;
        o.x = (unsigned)f2bf(eluf(acc.x * rden + bb.x)) | ((unsigned)f2bf(eluf(acc.y * rden + bb.y)) << 16);
        o.y = (unsigned)f2bf(eluf(acc.z * rden + bb.z)) | ((unsigned)f2bf(eluf(acc.w * rden + bb.w)) << 16);
        *(uint2*)(outb + ((size_t)h * NNODES + d) * 32 + t * 4) = o;
    }
}

// ---------------- GAT layer 2 aggregation: no-max softmax, late normalization --------
// (R7 version — best measured; one edge-visit per edge, wave per dst)
__global__ void gat2_agg_k(const u16* __restrict__ h2b, const float* __restrict__ as2,
                           const float* __restrict__ ad2, const int* __restrict__ rowptr,
                           const int* __restrict__ col, const float* __restrict__ b2,
                           float* __restrict__ emb){
    int lane = threadIdx.x & 63, wid = threadIdx.x >> 6;
    int d = blockIdx.x * 4 + wid;
    int row0 = rowptr[d];
    int deg  = rowptr[d + 1] - row0;

    float adst = ad2[d];
    float a_self = __expf(lrelu(as2[d] + adst));

    if (deg <= 64){
        int sv = (lane < deg) ? col[row0 + lane] : d;
        float e_raw = as2[sv];   // score gather

        int q = lane >> 4, c4 = (lane & 15) * 4;
        // prefetch self + chunk-0 rows while exps compute
        uint2 wself = *(const uint2*)(h2b + (unsigned)d * OUTC + c4);
        uint2 wpre[4];
#pragma unroll
        for (int k = 0; k < 4; k++){
            int s = __shfl(sv, k * 4 + q);
            wpre[k] = *(const uint2*)(h2b + (unsigned)s * OUTC + c4);
        }

        float x = (lane < deg) ? __expf(lrelu(e_raw + adst)) : 0.f;  // un-normalized alpha

        float a0 = (q == 0) ? a_self : 0.f;
        float4 acc = make_float4(0.f, 0.f, 0.f, 0.f);
        mac4(acc, wself, a0);
        // chunk 0 from prefetch
        {
            float a_arr[4];
#pragma unroll
            for (int k = 0; k < 4; k++) a_arr[k] = __shfl(x, k * 4 + q);
#pragma unroll
            for (int k = 0; k < 4; k++) mac4(acc, wpre[k], a_arr[k]);
        }
        for (int it0 = 16; it0 < deg; it0 += 16){
            int s_arr[4]; float a_arr[4];
#pragma unroll
            for (int k = 0; k < 4; k++){
                int itc = min(it0 + k * 4 + q, 63);
                s_arr[k] = __shfl(sv, itc);
                a_arr[k] = __shfl(x, itc);
            }
            uint2 w_arr[4];
#pragma unroll
            for (int k = 0; k < 4; k++)
                w_arr[k] = *(const uint2*)(h2b + (unsigned)s_arr[k] * OUTC + c4);
#pragma unroll
            for (int k = 0; k < 4; k++) mac4(acc, w_arr[k], a_arr[k]);
        }
        // channel reduce + vsum reduce (both after MACs)
        acc.x += __shfl_xor(acc.x, 16); acc.y += __shfl_xor(acc.y, 16);
        acc.z += __shfl_xor(acc.z, 16); acc.w += __shfl_xor(acc.w, 16);
        acc.x += __shfl_xor(acc.x, 32); acc.y += __shfl_xor(acc.y, 32);
        acc.z += __shfl_xor(acc.z, 32); acc.w += __shfl_xor(acc.w, 32);
        float vsum = x;
        for (int m = 1; m < 64; m <<= 1) vsum += __shfl_xor(vsum, m);
        float rden = 1.f / (vsum + a_self + EPS_F);
        if (lane < 16){
            float4 bb = *(const float4*)(b2 + c4);
            float4 o = make_float4(acc.x * rden + bb.x, acc.y * rden + bb.y,
                                   acc.z * rden + bb.z, acc.w * rden + bb.w);
            *(float4*)(emb + (size_t)d * OUTC + c4) = o;
        }
    } else {
        // single-pass: uniform per-edge alpha, lane owns one channel
        float vsum = a_self;
        float acc = a_self * h2f(h2b[(unsigned)d * OUTC + lane]);
        for (int idx = 0; idx < deg; idx++){
            int s = col[row0 + idx];
            float a = __expf(lrelu(as2[s] + adst));
            vsum += a;
            acc += a * h2f(h2b[(unsigned)s * OUTC + lane]);
        }
        emb[(size_t)d * OUTC + lane] = acc * (1.f / (vsum + EPS_F)) + b2[lane];
    }
}

// ---------------- MLP head + softmax via MFMA ----------------
__global__ void mlp_mfma_k(const float* __restrict__ emb, const u16* __restrict__ W1mt,
                           const float* __restrict__ bm1, const u16* __restrict__ W2mt,
                           const float* __restrict__ bm2, float* __restrict__ sout){
    __shared__ u16 hid[4][16][136];
    int lane = threadIdx.x & 63, wid = threadIdx.x >> 6;
    int ln = lane & 15, quad = lane >> 4;
    int m0 = blockIdx.x * 64 + wid * 16;
    int arow = m0 + ln; if (arow >= NNODES) arow = NNODES - 1;

    bf16x8 a[2];
#pragma unroll
    for (int kt = 0; kt < 2; kt++){
        const float* ap = emb + (size_t)arow * OUTC + kt * 32 + quad * 8;
        float4 v0 = *(const float4*)ap;
        float4 v1 = *(const float4*)(ap + 4);
        bf16x8 t;
        t[0] = f2bf_s(v0.x); t[1] = f2bf_s(v0.y); t[2] = f2bf_s(v0.z); t[3] = f2bf_s(v0.w);
        t[4] = f2bf_s(v1.x); t[5] = f2bf_s(v1.y); t[6] = f2bf_s(v1.z); t[7] = f2bf_s(v1.w);
        a[kt] = t;
    }

    f32x4 acc[8];
#pragma unroll
    for (int nt = 0; nt < 8; nt++) acc[nt] = (f32x4){0.f, 0.f, 0.f, 0.f};
#pragma unroll
    for (int kt = 0; kt < 2; kt++){
#pragma unroll
        for (int nt = 0; nt < 8; nt++){
            bf16x8 b = *(const bf16x8*)(W1mt + (size_t)(nt * 16 + ln) * OUTC + kt * 32 + quad * 8);
            acc[nt] = __builtin_amdgcn_mfma_f32_16x16x32_bf16(a[kt], b, acc[nt], 0, 0, 0);
        }
    }

#pragma unroll
    for (int nt = 0; nt < 8; nt++){
        float bb = bm1[nt * 16 + ln];
#pragma unroll
        for (int i = 0; i < 4; i++){
            float h = fmaxf(acc[nt][i] + bb, 0.f);
            hid[wid][quad * 4 + i][nt * 16 + ln] = f2bf(h);
        }
    }

    f32x4 acc2 = (f32x4){0.f, 0.f, 0.f, 0.f};
#pragma unroll
    for (int kt = 0; kt < 4; kt++){
        bf16x8 ah = *(const bf16x8*)&hid[wid][ln][kt * 32 + quad * 8];
        bf16x8 bw = *(const bf16x8*)(W2mt + (size_t)ln * 128 + kt * 32 + quad * 8);
        acc2 = __builtin_amdgcn_mfma_f32_16x16x32_bf16(ah, bw, acc2, 0, 0, 0);
    }

    float bcl = bm2[ln];
#pragma unroll
    for (int i = 0; i < 4; i++){
        int r = m0 + quad * 4 + i;
        float lg = acc2[i] + bcl;
        float m = lg;
        m = fmaxf(m, __shfl_xor(m, 1));
        m = fmaxf(m, __shfl_xor(m, 2));
        m = fmaxf(m, __shfl_xor(m, 4));
        m = fmaxf(m, __shfl_xor(m, 8));
        float ex = __expf(lg - m);
        float s = ex;
        s += __shfl_xor(s, 1);
        s += __shfl_xor(s, 2);
        s += __shfl_xor(s, 4);
        s += __shfl_xor(s, 8);
        if (r < NNODES) sout[(size_t)r * NK + ln] = ex / s;
    }
}

// ---------------- launcher ----------------
extern "C" void kernel_launch(void* const* d_in, const int* in_sizes, int n_in,
                              void* d_out, int out_size, void* d_ws, size_t ws_size,
                              hipStream_t stream){
    const float* x      = (const float*)d_in[0];
    const int*   ei     = (const int*)d_in[1];
    const int*   srcv   = ei;
    const int*   dstv   = ei + NEDGES;
    const float* W1     = (const float*)d_in[2];
    const float* att_s1 = (const float*)d_in[3];
    const float* att_d1 = (const float*)d_in[4];
    const float* b1     = (const float*)d_in[5];
    const float* W2     = (const float*)d_in[6];
    const float* att_s2 = (const float*)d_in[7];
    const float* att_d2 = (const float*)d_in[8];
    const float* b2     = (const float*)d_in[9];
    const float* Wm1    = (const float*)d_in[10];
    const float* bm1    = (const float*)d_in[11];
    const float* Wm2    = (const float*)d_in[12];
    const float* bm2    = (const float*)d_in[13];

    float* out     = (float*)d_out;                     // s: [N,16]
    float* emb_out = out + (size_t)NNODES * NK;         // embeddings: [N,64]

    u16* h1b   = (u16*)d_ws;                            // [8][N][32] f16
    u16* hL1b  = h1b  + (size_t)NNODES * HC1;           // [8][N][32] bf16
    u16* h2b   = hL1b + (size_t)NNODES * HC1;           // N*64 f16 (row-major)
    u16* W1t   = h2b  + (size_t)NNODES * OUTC;          // 256*128
    u16* W2t   = W1t + 256 * 128;                       // 64*256
    u16* W1mt  = W2t + 64 * 256;                        // 128*64
    u16* W2mt  = W1mt + 128 * 64;                       // 16*128
    float* as1 = (float*)(W2mt + 16 * 128);             // [8][N]
    float* ad1 = as1 + (size_t)NNODES * NHEADS;         // [8][N]
    float* as2 = ad1 + (size_t)NNODES * NHEADS;         // N
    float* ad2 = as2 + NNODES;                          // N
    int* deg    = (int*)(ad2 + NNODES);                 // N   (deg+fillc adjacent -> 1 memset)
    int* fillc  = deg + NNODES;                         // N
    int* rowptr = fillc + NNODES;                       // N+1
    int* bsum   = rowptr + NNODES + 1;                  // 256
    int* colv   = bsum + 256;                           // E

    hipMemsetAsync(deg, 0, 2 * NNODES * sizeof(int), stream);

    const int NB = (NNODES + 255) / 256;   // 196

    count_deg_tw_k<<<EB + TB, 256, 0, stream>>>(dstv, deg, W1, W1t, W2, W2t, Wm1, W1mt, Wm2, W2mt);
    blocksum_k<<<NB, 256, 0, stream>>>(deg, bsum);
    scan_write_k<<<NB, 256, 0, stream>>>(deg, bsum, rowptr);

    // fused: fill_csr (EB blocks) + l1 (2*MBD blocks) — independent work, one dispatch
    fill_l1_k<<<EB + 2 * MBD, 256, 0, stream>>>(srcv, dstv, rowptr, fillc, colv,
                                                x, W1t, att_s1, att_d1, h1b, as1, ad1);

    // head-partitioned: 8 heads x ceil(N/32) node-chunks; head = blockIdx & 7 -> XCD id
    gat1_agg_k<<<8 * ((NNODES + 31) / 32), 256, 0, stream>>>(h1b, as1, ad1, rowptr, colv, b1, hL1b);

    l2_k<<<MBD, 256, 0, stream>>>(hL1b, W2t, att_s2, att_d2, h2b, as2, ad2);
    gat2_agg_k<<<NNODES / 4, 256, 0, stream>>>(h2b, as2, ad2, rowptr, colv, b2, emb_out);

    mlp_mfma_k<<<MBD, 256, 0, stream>>>(emb_out, W1mt, bm1, W2mt, bm2, out);
}

// Round 11
// 232.763 us; speedup vs baseline: 1.1737x; 1.0679x over previous
//
#include <hip/hip_runtime.h>
#include <hip/hip_fp16.h>
#include <math.h>

#define NNODES 50000
#define NEDGES 400000
#define INC    128
#define HC1    256   // HEADS*HID
#define NHEADS 8
#define OUTC   64
#define NK     16
#define NEG_SLOPE 0.2f
#define EPS_F  1e-16f

typedef unsigned short u16;
typedef __attribute__((ext_vector_type(8))) short bf16x8;
typedef __attribute__((ext_vector_type(4))) float f32x4;

__device__ __forceinline__ float lrelu(float x){ return x > 0.f ? x : NEG_SLOPE * x; }
__device__ __forceinline__ float eluf(float x){ return x > 0.f ? x : (__expf(x) - 1.f); }
__device__ __forceinline__ float bf2f(u16 v){ return __uint_as_float((unsigned)v << 16); }
__device__ __forceinline__ u16 f2bf(float f){
    unsigned u = __float_as_uint(f);
    unsigned r = (u + 0x7FFFu + ((u >> 16) & 1u)) >> 16;   // RTNE
    return (u16)r;
}
__device__ __forceinline__ short f2bf_s(float f){ return (short)f2bf(f); }
__device__ __forceinline__ u16 f2h(float f){ return __half_as_ushort(__float2half(f)); }
__device__ __forceinline__ float h2f(u16 v){ return __half2float(__ushort_as_half(v)); }

// hw packed f32x2 -> bf16x2 (RTNE), 1 instruction (no builtin on gfx950)
__device__ __forceinline__ unsigned cvtpk_bf16(float lo, float hi){
    unsigned r;
    asm("v_cvt_pk_bf16_f32 %0, %1, %2" : "=v"(r) : "v"(lo), "v"(hi));
    return r;
}

// one-instruction f16*f32+f32 MAC (no unpack)
__device__ __forceinline__ void fmix_lo(float& acc, unsigned w, float a){
    asm("v_fma_mix_f32 %0, %1, %2, %0 op_sel:[0,0,0] op_sel_hi:[1,0,0]"
        : "+v"(acc) : "v"(w), "v"(a));
}
__device__ __forceinline__ void fmix_hi(float& acc, unsigned w, float a){
    asm("v_fma_mix_f32 %0, %1, %2, %0 op_sel:[1,0,0] op_sel_hi:[1,0,0]"
        : "+v"(acc) : "v"(w), "v"(a));
}
__device__ __forceinline__ void mac8(float* acc, uint4 w, float a){
    fmix_lo(acc[0], w.x, a); fmix_hi(acc[1], w.x, a);
    fmix_lo(acc[2], w.y, a); fmix_hi(acc[3], w.y, a);
    fmix_lo(acc[4], w.z, a); fmix_hi(acc[5], w.z, a);
    fmix_lo(acc[6], w.w, a); fmix_hi(acc[7], w.w, a);
}
__device__ __forceinline__ void mac4(float4& acc, uint2 w, float a){
    fmix_lo(acc.x, w.x, a); fmix_hi(acc.y, w.x, a);
    fmix_lo(acc.z, w.y, a); fmix_hi(acc.w, w.y, a);
}

// ---------------- CSR build + weight prep ----------------
#define EB 1563   // ceil(400000/256)
#define TB 232    // ceil(59392/256)
#define MBD 782   // ceil(50000/64)
// count pass also records each edge's within-row position -> fill needs no atomics
__global__ void count_deg_tw_k(const int* __restrict__ dst, int* __restrict__ deg,
                               int* __restrict__ pose,
                               const float* __restrict__ W1, u16* __restrict__ W1t,
                               const float* __restrict__ W2, u16* __restrict__ W2t,
                               const float* __restrict__ Wm1, u16* __restrict__ W1mt,
                               const float* __restrict__ Wm2, u16* __restrict__ W2mt){
    if (blockIdx.x < EB){
        int e = blockIdx.x * 256 + threadIdx.x;
        if (e < NEDGES) pose[e] = atomicAdd(&deg[dst[e]], 1);
    } else {
        int i = (blockIdx.x - EB) * 256 + threadIdx.x;   // < 59392
        if (i < 32768){
            int n = i >> 7, k = i & 127;
            W1t[i] = f2bf(W1[k * 256 + n]);
        } else if (i < 49152){
            int ii = i - 32768;
            int n = ii >> 8, k = ii & 255;
            W2t[ii] = f2bf(W2[k * 64 + n]);
        } else if (i < 57344){
            int ii = i - 49152;
            int hd = ii >> 6, e = ii & 63;
            W1mt[ii] = f2bf(Wm1[e * 128 + hd]);
        } else if (i < 59392){
            int ii = i - 57344;
            int k = ii >> 7, hd = ii & 127;
            W2mt[ii] = f2bf(Wm2[hd * NK + k]);
        }
    }
}

__global__ void blocksum_k(const int* __restrict__ deg, int* __restrict__ bsum){
    __shared__ int sm[4];
    int i = blockIdx.x * 256 + threadIdx.x;
    int v = (i < NNODES) ? deg[i] : 0;
    for (int off = 1; off < 64; off <<= 1) v += __shfl_xor(v, off);
    int lane = threadIdx.x & 63, wid = threadIdx.x >> 6;
    if (lane == 0) sm[wid] = v;
    __syncthreads();
    if (threadIdx.x == 0) bsum[blockIdx.x] = sm[0] + sm[1] + sm[2] + sm[3];
}

__global__ void scan_write_k(const int* __restrict__ deg, const int* __restrict__ bsum,
                             int* __restrict__ rowptr){
    __shared__ int sm[4];
    __shared__ int sadd;
    int tid = threadIdx.x;
    int pv = (tid < blockIdx.x) ? bsum[tid] : 0;   // NB=196 < 256
    for (int off = 1; off < 64; off <<= 1) pv += __shfl_xor(pv, off);
    int lane = tid & 63, wid = tid >> 6;
    if (lane == 0) sm[wid] = pv;
    __syncthreads();
    if (tid == 0) sadd = sm[0] + sm[1] + sm[2] + sm[3];
    __syncthreads();

    int i = blockIdx.x * 256 + tid;
    int v = (i < NNODES) ? deg[i] : 0;
    int sv = v;
    for (int off = 1; off < 64; off <<= 1){ int t = __shfl_up(sv, off); if (lane >= off) sv += t; }
    __shared__ int wsum[4];
    if (lane == 63) wsum[wid] = sv;
    __syncthreads();
    int add = sadd;
    for (int w = 0; w < wid; w++) add += wsum[w];
    sv += add;
    if (i < NNODES) rowptr[i + 1] = sv;
    if (i == 0) rowptr[0] = 0;
}

// ---------------- FUSED: fill_csr (blocks 0..EB-1, atomic-free) + L1 ----------------
// L1: h1bh[8][N][32] = f16(x @ W1) head-major, fused att1.
// l1 branch pre-issues all 8 x-float4 loads before staging (load MLP), converts with
// v_cvt_pk_bf16_f32 after the barrier.
__global__ __launch_bounds__(256, 4) void fill_l1_k(
        const int* __restrict__ src, const int* __restrict__ dstv,
        const int* __restrict__ rowptr, const int* __restrict__ pose, int* __restrict__ col,
        const float* __restrict__ x, const u16* __restrict__ W1t,
        const float* __restrict__ att_s, const float* __restrict__ att_d,
        u16* __restrict__ h1bh, float* __restrict__ as1h, float* __restrict__ ad1h){
    __shared__ u16 Bs[16384];   // 32 KB (l1 branch only)
    if (blockIdx.x < EB){
        int e = blockIdx.x * 256 + threadIdx.x;
        if (e < NEDGES){
            int d = dstv[e];
            col[rowptr[d] + pose[e]] = src[e];   // non-atomic scatter
        }
        return;
    }
    int li = blockIdx.x - EB;             // 0..2*MBD-1
    int by = (li >= MBD) ? 1 : 0;
    int bx = li - by * MBD;

    int tid = threadIdx.x;
    int lane = tid & 63, wid = tid >> 6;
    int ln = lane & 15, quad = lane >> 4;
    int m0 = bx * 64 + wid * 16;
    int nb = by * 128;            // col base: 0 or 128
    int hb = by * 4;              // head base: 0 or 4
    int arow = m0 + ln; if (arow >= NNODES) arow = NNODES - 1;

    // (1) pre-issue ALL x loads (8 float4 = 32 VGPR) so they fly with staging
    const float* xb = x + (size_t)arow * INC + quad * 8;
    float4 xv0[4], xv1[4];
#pragma unroll
    for (int kt = 0; kt < 4; kt++){
        xv0[kt] = *(const float4*)(xb + kt * 32);
        xv1[kt] = *(const float4*)(xb + kt * 32 + 4);
    }

    // (2) stage W1t[nb..nb+128) into LDS (fragment order); 8 independent 16B loads/thread
#pragma unroll
    for (int it = 0; it < 8; it++){
        int p = it * 256 + tid;          // 0..2047
        int c = p >> 6, l = p & 63;
        int snt = c & 7, skt = c >> 3;
        int sln = l & 15, sq = l >> 4;
        uint4 v = *(const uint4*)(W1t + (size_t)(nb + snt * 16 + sln) * INC + skt * 32 + sq * 8);
        *(uint4*)(&Bs[p * 8]) = v;
    }

    __syncthreads();

    // (3) convert x -> bf16 frags with packed hw converts (1 instr / 2 vals)
    bf16x8 a[4];
#pragma unroll
    for (int kt = 0; kt < 4; kt++){
        union { unsigned u[4]; bf16x8 v; } cv;
        cv.u[0] = cvtpk_bf16(xv0[kt].x, xv0[kt].y);
        cv.u[1] = cvtpk_bf16(xv0[kt].z, xv0[kt].w);
        cv.u[2] = cvtpk_bf16(xv1[kt].x, xv1[kt].y);
        cv.u[3] = cvtpk_bf16(xv1[kt].z, xv1[kt].w);
        a[kt] = cv.v;
    }

    f32x4 acc[8];
#pragma unroll
    for (int nt = 0; nt < 8; nt++) acc[nt] = (f32x4){0.f, 0.f, 0.f, 0.f};

#pragma unroll
    for (int kt = 0; kt < 4; kt++){
#pragma unroll
        for (int nt = 0; nt < 8; nt++){
            bf16x8 b = *(const bf16x8*)(&Bs[(kt * 8 + nt) * 512 + lane * 8]);
            acc[nt] = __builtin_amdgcn_mfma_f32_16x16x32_bf16(a[kt], b, acc[nt], 0, 0, 0);
        }
    }

    // h1b write: head-major [h][N][32] f16
#pragma unroll
    for (int i = 0; i < 4; i++){
        int r = m0 + quad * 4 + i;
        if (r < NNODES){
#pragma unroll
            for (int nt = 0; nt < 8; nt++){
                int c  = nb + nt * 16 + ln;      // global channel
                int hh = c >> 5, c5 = c & 31;
                h1bh[((size_t)hh * NNODES + r) * 32 + c5] = f2h(acc[nt][i]);
            }
        }
    }

#pragma unroll
    for (int i = 0; i < 4; i++){
        int r = m0 + quad * 4 + i;
        float ps_keep = 0.f, pd_keep = 0.f;
#pragma unroll
        for (int h = 0; h < 4; h++){
            float ps = acc[2 * h][i]     * att_s[nb + h * 32 + ln]
                     + acc[2 * h + 1][i] * att_s[nb + h * 32 + 16 + ln];
            float pd = acc[2 * h][i]     * att_d[nb + h * 32 + ln]
                     + acc[2 * h + 1][i] * att_d[nb + h * 32 + 16 + ln];
            ps += __shfl_xor(ps, 1); pd += __shfl_xor(pd, 1);
            ps += __shfl_xor(ps, 2); pd += __shfl_xor(pd, 2);
            ps += __shfl_xor(ps, 4); pd += __shfl_xor(pd, 4);
            ps += __shfl_xor(ps, 8); pd += __shfl_xor(pd, 8);
            if (ln == h){ ps_keep = ps; pd_keep = pd; }
        }
        if (ln < 4 && r < NNODES){
            as1h[(size_t)(hb + ln) * NNODES + r] = ps_keep;
            ad1h[(size_t)(hb + ln) * NNODES + r] = pd_keep;
        }
    }
}

// ---------------- L2: h2b[N,64] = f16(hL1b @ W2), fused att2 (LDS-staged B) ----------
// hL1b is head-major [8][N][32] bf16: A-frag for k-tile kt = head kt.
__global__ __launch_bounds__(256, 4) void l2_k(const u16* __restrict__ hL1b, const u16* __restrict__ W2t,
                     const float* __restrict__ att_s, const float* __restrict__ att_d,
                     u16* __restrict__ h2b, float* __restrict__ as2, float* __restrict__ ad2){
    __shared__ u16 Bs[16384];   // 32 KB: chunk c=(kt*4+nt), kt in [0,8), nt in [0,4)
    int tid = threadIdx.x;
    int lane = tid & 63, wid = tid >> 6;
    int ln = lane & 15, quad = lane >> 4;
    int m0 = blockIdx.x * 64 + wid * 16;
    int arow = m0 + ln; if (arow >= NNODES) arow = NNODES - 1;

#pragma unroll
    for (int it = 0; it < 8; it++){
        int p = it * 256 + tid;          // 0..2047
        int c = p >> 6, l = p & 63;
        int snt = c & 3, skt = c >> 2;
        int sln = l & 15, sq = l >> 4;
        uint4 v = *(const uint4*)(W2t + (size_t)(snt * 16 + sln) * HC1 + skt * 32 + sq * 8);
        *(uint4*)(&Bs[p * 8]) = v;
    }

    __syncthreads();

    f32x4 acc[4];
#pragma unroll
    for (int nt = 0; nt < 4; nt++) acc[nt] = (f32x4){0.f, 0.f, 0.f, 0.f};

#pragma unroll
    for (int kt = 0; kt < 8; kt++){
        bf16x8 a = *(const bf16x8*)(hL1b + ((size_t)kt * NNODES + arow) * 32 + quad * 8);
#pragma unroll
        for (int nt = 0; nt < 4; nt++){
            bf16x8 b = *(const bf16x8*)(&Bs[(kt * 4 + nt) * 512 + lane * 8]);
            acc[nt] = __builtin_amdgcn_mfma_f32_16x16x32_bf16(a, b, acc[nt], 0, 0, 0);
        }
    }

#pragma unroll
    for (int i = 0; i < 4; i++){
        int r = m0 + quad * 4 + i;
        if (r < NNODES){
#pragma unroll
            for (int nt = 0; nt < 4; nt++)
                h2b[(size_t)r * OUTC + nt * 16 + ln] = f2h(acc[nt][i]);
        }
        float ps = acc[0][i] * att_s[ln]      + acc[1][i] * att_s[16 + ln]
                 + acc[2][i] * att_s[32 + ln] + acc[3][i] * att_s[48 + ln];
        float pd = acc[0][i] * att_d[ln]      + acc[1][i] * att_d[16 + ln]
                 + acc[2][i] * att_d[32 + ln] + acc[3][i] * att_d[48 + ln];
        ps += __shfl_xor(ps, 1); pd += __shfl_xor(pd, 1);
        ps += __shfl_xor(ps, 2); pd += __shfl_xor(pd, 2);
        ps += __shfl_xor(ps, 4); pd += __shfl_xor(pd, 4);
        ps += __shfl_xor(ps, 8); pd += __shfl_xor(pd, 8);
        if (ln == 0 && r < NNODES){ as2[r] = ps; ad2[r] = pd; }
    }
}

// ---------------- GAT layer 1 aggregation: head-partitioned, no-max softmax, --------
// late normalization (best measured: 45.7us). 8-lane group per (dst,head).
__global__ void gat1_agg_k(const u16* __restrict__ h1bh, const float* __restrict__ as1h,
                           const float* __restrict__ ad1h, const int* __restrict__ rowptr,
                           const int* __restrict__ col, const float* __restrict__ b1,
                           u16* __restrict__ outb){
    int lane = threadIdx.x & 63, wid = threadIdx.x >> 6;
    int g = lane >> 3, t = lane & 7;
    int h = blockIdx.x & 7;
    int d = (blockIdx.x >> 3) * 32 + wid * 8 + g;
    bool valid = (d < NNODES);
    int dd = valid ? d : (NNODES - 1);
    int row0 = rowptr[dd];
    int deg  = rowptr[dd + 1] - row0;

    const float* ash = as1h + (size_t)h * NNODES;
    float adst = ad1h[(size_t)h * NNODES + dd];
    const u16* hb = h1bh + (size_t)h * NNODES * 32;

    // col loads (round 1), then score gathers + self row (round 2, concurrent)
    int sv0 = (t < deg)     ? col[row0 + t]     : dd;
    int sv1 = (8 + t < deg) ? col[row0 + 8 + t] : dd;
    uint2 wself = *(const uint2*)(hb + (size_t)dd * 32 + t * 4);
    float ev0 = ash[sv0];
    float ev1 = ash[sv1];

    float a_self = __expf(lrelu(ash[dd] + adst));
    float x0 = (t < deg)     ? __expf(lrelu(ev0 + adst)) : 0.f;
    float x1 = (8 + t < deg) ? __expf(lrelu(ev1 + adst)) : 0.f;

    float4 acc = make_float4(0.f, 0.f, 0.f, 0.f);
    mac4(acc, wself, a_self);

    int gb = g * 8;
    if (deg > 0){
        int s_arr[4]; float a_arr[4]; uint2 w_arr[4];
#pragma unroll
        for (int j = 0; j < 4; j++){ s_arr[j] = __shfl(sv0, gb + j); a_arr[j] = __shfl(x0, gb + j); }
#pragma unroll
        for (int j = 0; j < 4; j++) w_arr[j] = *(const uint2*)(hb + (size_t)s_arr[j] * 32 + t * 4);
#pragma unroll
        for (int j = 0; j < 4; j++) mac4(acc, w_arr[j], a_arr[j]);
        if (deg > 4){
#pragma unroll
            for (int j = 0; j < 4; j++){ s_arr[j] = __shfl(sv0, gb + 4 + j); a_arr[j] = __shfl(x0, gb + 4 + j); }
#pragma unroll
            for (int j = 0; j < 4; j++) w_arr[j] = *(const uint2*)(hb + (size_t)s_arr[j] * 32 + t * 4);
#pragma unroll
            for (int j = 0; j < 4; j++) mac4(acc, w_arr[j], a_arr[j]);
        }
    }
    if (deg > 8){
        int s_arr[4]; float a_arr[4]; uint2 w_arr[4];
#pragma unroll
        for (int j = 0; j < 4; j++){ s_arr[j] = __shfl(sv1, gb + j); a_arr[j] = __shfl(x1, gb + j); }
#pragma unroll
        for (int j = 0; j < 4; j++) w_arr[j] = *(const uint2*)(hb + (size_t)s_arr[j] * 32 + t * 4);
#pragma unroll
        for (int j = 0; j < 4; j++) mac4(acc, w_arr[j], a_arr[j]);
        if (deg > 12){
#pragma unroll
            for (int j = 0; j < 4; j++){ s_arr[j] = __shfl(sv1, gb + 4 + j); a_arr[j] = __shfl(x1, gb + 4 + j); }
#pragma unroll
            for (int j = 0; j < 4; j++) w_arr[j] = *(const uint2*)(hb + (size_t)s_arr[j] * 32 + t * 4);
#pragma unroll
            for (int j = 0; j < 4; j++) mac4(acc, w_arr[j], a_arr[j]);
        }
    }
    float tsum = 0.f;
    if (deg > 16){
        for (int idx = 16; idx < deg; idx++){
            int s = col[row0 + idx];   // group-uniform
            float a = __expf(lrelu(ash[s] + adst));
            tsum += a;                 // uniform across the 8-lane group
            uint2 w = *(const uint2*)(hb + (size_t)s * 32 + t * 4);
            mac4(acc, w, a);
        }
    }

    // vsum reduction AFTER the MACs (off the critical path)
    float part = x0 + x1;
    part += __shfl_xor(part, 1);
    part += __shfl_xor(part, 2);
    part += __shfl_xor(part, 4);
    float rden = 1.f / (part + a_self + tsum + EPS_F);

    if (valid){
        float4 bb = *(const float4*)(b1 + h * 32 + t * 4);
        uint2 o;
        o.x = (unsigned)f2bf(eluf(acc.x * rden + bb.x)) | ((unsigned)f2bf(eluf(acc.y * rden + bb.y)) << 16);
        o.y = (unsigned)f2bf(eluf(acc.z * rden + bb.z)) | ((unsigned)f2bf(eluf(acc.w * rden + bb.w)) << 16);
        *(uint2*)(outb + ((size_t)h * NNODES + d) * 32 + t * 4) = o;
    }
}

// ---------------- GAT layer 2 aggregation: no-max softmax, late normalization --------
// (best measured; one edge-visit per edge, wave per dst)
__global__ void gat2_agg_k(const u16* __restrict__ h2b, const float* __restrict__ as2,
                           const float* __restrict__ ad2, const int* __restrict__ rowptr,
                           const int* __restrict__ col, const float* __restrict__ b2,
                           float* __restrict__ emb){
    int lane = threadIdx.x & 63, wid = threadIdx.x >> 6;
    int d = blockIdx.x * 4 + wid;
    int row0 = rowptr[d];
    int deg  = rowptr[d + 1] - row0;

    float adst = ad2[d];
    float a_self = __expf(lrelu(as2[d] + adst));

    if (deg <= 64){
        int sv = (lane < deg) ? col[row0 + lane] : d;
        float e_raw = as2[sv];   // score gather

        int q = lane >> 4, c4 = (lane & 15) * 4;
        // prefetch self + chunk-0 rows while exps compute
        uint2 wself = *(const uint2*)(h2b + (unsigned)d * OUTC + c4);
        uint2 wpre[4];
#pragma unroll
        for (int k = 0; k < 4; k++){
            int s = __shfl(sv, k * 4 + q);
            wpre[k] = *(const uint2*)(h2b + (unsigned)s * OUTC + c4);
        }

        float x = (lane < deg) ? __expf(lrelu(e_raw + adst)) : 0.f;  // un-normalized alpha

        float a0 = (q == 0) ? a_self : 0.f;
        float4 acc = make_float4(0.f, 0.f, 0.f, 0.f);
        mac4(acc, wself, a0);
        // chunk 0 from prefetch
        {
            float a_arr[4];
#pragma unroll
            for (int k = 0; k < 4; k++) a_arr[k] = __shfl(x, k * 4 + q);
#pragma unroll
            for (int k = 0; k < 4; k++) mac4(acc, wpre[k], a_arr[k]);
        }
        for (int it0 = 16; it0 < deg; it0 += 16){
            int s_arr[4]; float a_arr[4];
#pragma unroll
            for (int k = 0; k < 4; k++){
                int itc = min(it0 + k * 4 + q, 63);
                s_arr[k] = __shfl(sv, itc);
                a_arr[k] = __shfl(x, itc);
            }
            uint2 w_arr[4];
#pragma unroll
            for (int k = 0; k < 4; k++)
                w_arr[k] = *(const uint2*)(h2b + (unsigned)s_arr[k] * OUTC + c4);
#pragma unroll
            for (int k = 0; k < 4; k++) mac4(acc, w_arr[k], a_arr[k]);
        }
        // channel reduce + vsum reduce (both after MACs)
        acc.x += __shfl_xor(acc.x, 16); acc.y += __shfl_xor(acc.y, 16);
        acc.z += __shfl_xor(acc.z, 16); acc.w += __shfl_xor(acc.w, 16);
        acc.x += __shfl_xor(acc.x, 32); acc.y += __shfl_xor(acc.y, 32);
        acc.z += __shfl_xor(acc.z, 32); acc.w += __shfl_xor(acc.w, 32);
        float vsum = x;
        for (int m = 1; m < 64; m <<= 1) vsum += __shfl_xor(vsum, m);
        float rden = 1.f / (vsum + a_self + EPS_F);
        if (lane < 16){
            float4 bb = *(const float4*)(b2 + c4);
            float4 o = make_float4(acc.x * rden + bb.x, acc.y * rden + bb.y,
                                   acc.z * rden + bb.z, acc.w * rden + bb.w);
            *(float4*)(emb + (size_t)d * OUTC + c4) = o;
        }
    } else {
        // single-pass: uniform per-edge alpha, lane owns one channel
        float vsum = a_self;
        float acc = a_self * h2f(h2b[(unsigned)d * OUTC + lane]);
        for (int idx = 0; idx < deg; idx++){
            int s = col[row0 + idx];
            float a = __expf(lrelu(as2[s] + adst));
            vsum += a;
            acc += a * h2f(h2b[(unsigned)s * OUTC + lane]);
        }
        emb[(size_t)d * OUTC + lane] = acc * (1.f / (vsum + EPS_F)) + b2[lane];
    }
}

// ---------------- MLP head + softmax via MFMA ----------------
__global__ void mlp_mfma_k(const float* __restrict__ emb, const u16* __restrict__ W1mt,
                           const float* __restrict__ bm1, const u16* __restrict__ W2mt,
                           const float* __restrict__ bm2, float* __restrict__ sout){
    __shared__ u16 hid[4][16][136];
    int lane = threadIdx.x & 63, wid = threadIdx.x >> 6;
    int ln = lane & 15, quad = lane >> 4;
    int m0 = blockIdx.x * 64 + wid * 16;
    int arow = m0 + ln; if (arow >= NNODES) arow = NNODES - 1;

    bf16x8 a[2];
#pragma unroll
    for (int kt = 0; kt < 2; kt++){
        const float* ap = emb + (size_t)arow * OUTC + kt * 32 + quad * 8;
        float4 v0 = *(const float4*)ap;
        float4 v1 = *(const float4*)(ap + 4);
        union { unsigned u[4]; bf16x8 v; } cv;
        cv.u[0] = cvtpk_bf16(v0.x, v0.y);
        cv.u[1] = cvtpk_bf16(v0.z, v0.w);
        cv.u[2] = cvtpk_bf16(v1.x, v1.y);
        cv.u[3] = cvtpk_bf16(v1.z, v1.w);
        a[kt] = cv.v;
    }

    f32x4 acc[8];
#pragma unroll
    for (int nt = 0; nt < 8; nt++) acc[nt] = (f32x4){0.f, 0.f, 0.f, 0.f};
#pragma unroll
    for (int kt = 0; kt < 2; kt++){
#pragma unroll
        for (int nt = 0; nt < 8; nt++){
            bf16x8 b = *(const bf16x8*)(W1mt + (size_t)(nt * 16 + ln) * OUTC + kt * 32 + quad * 8);
            acc[nt] = __builtin_amdgcn_mfma_f32_16x16x32_bf16(a[kt], b, acc[nt], 0, 0, 0);
        }
    }

#pragma unroll
    for (int nt = 0; nt < 8; nt++){
        float bb = bm1[nt * 16 + ln];
#pragma unroll
        for (int i = 0; i < 4; i++){
            float h = fmaxf(acc[nt][i] + bb, 0.f);
            hid[wid][quad * 4 + i][nt * 16 + ln] = f2bf(h);
        }
    }

    f32x4 acc2 = (f32x4){0.f, 0.f, 0.f, 0.f};
#pragma unroll
    for (int kt = 0; kt < 4; kt++){
        bf16x8 ah = *(const bf16x8*)&hid[wid][ln][kt * 32 + quad * 8];
        bf16x8 bw = *(const bf16x8*)(W2mt + (size_t)ln * 128 + kt * 32 + quad * 8);
        acc2 = __builtin_amdgcn_mfma_f32_16x16x32_bf16(ah, bw, acc2, 0, 0, 0);
    }

    float bcl = bm2[ln];
#pragma unroll
    for (int i = 0; i < 4; i++){
        int r = m0 + quad * 4 + i;
        float lg = acc2[i] + bcl;
        float m = lg;
        m = fmaxf(m, __shfl_xor(m, 1));
        m = fmaxf(m, __shfl_xor(m, 2));
        m = fmaxf(m, __shfl_xor(m, 4));
        m = fmaxf(m, __shfl_xor(m, 8));
        float ex = __expf(lg - m);
        float s = ex;
        s += __shfl_xor(s, 1);
        s += __shfl_xor(s, 2);
        s += __shfl_xor(s, 4);
        s += __shfl_xor(s, 8);
        if (r < NNODES) sout[(size_t)r * NK + ln] = ex / s;
    }
}

// ---------------- launcher ----------------
extern "C" void kernel_launch(void* const* d_in, const int* in_sizes, int n_in,
                              void* d_out, int out_size, void* d_ws, size_t ws_size,
                              hipStream_t stream){
    const float* x      = (const float*)d_in[0];
    const int*   ei     = (const int*)d_in[1];
    const int*   srcv   = ei;
    const int*   dstv   = ei + NEDGES;
    const float* W1     = (const float*)d_in[2];
    const float* att_s1 = (const float*)d_in[3];
    const float* att_d1 = (const float*)d_in[4];
    const float* b1     = (const float*)d_in[5];
    const float* W2     = (const float*)d_in[6];
    const float* att_s2 = (const float*)d_in[7];
    const float* att_d2 = (const float*)d_in[8];
    const float* b2     = (const float*)d_in[9];
    const float* Wm1    = (const float*)d_in[10];
    const float* bm1    = (const float*)d_in[11];
    const float* Wm2    = (const float*)d_in[12];
    const float* bm2    = (const float*)d_in[13];

    float* out     = (float*)d_out;                     // s: [N,16]
    float* emb_out = out + (size_t)NNODES * NK;         // embeddings: [N,64]

    u16* h1b   = (u16*)d_ws;                            // [8][N][32] f16
    u16* hL1b  = h1b  + (size_t)NNODES * HC1;           // [8][N][32] bf16
    u16* h2b   = hL1b + (size_t)NNODES * HC1;           // N*64 f16 (row-major)
    u16* W1t   = h2b  + (size_t)NNODES * OUTC;          // 256*128
    u16* W2t   = W1t + 256 * 128;                       // 64*256
    u16* W1mt  = W2t + 64 * 256;                        // 128*64
    u16* W2mt  = W1mt + 128 * 64;                       // 16*128
    float* as1 = (float*)(W2mt + 16 * 128);             // [8][N]
    float* ad1 = as1 + (size_t)NNODES * NHEADS;         // [8][N]
    float* as2 = ad1 + (size_t)NNODES * NHEADS;         // N
    float* ad2 = as2 + NNODES;                          // N
    int* deg    = (int*)(ad2 + NNODES);                 // N   (deg+fillc adjacent -> 1 memset)
    int* fillc  = deg + NNODES;                         // N (unused now, kept for layout)
    int* rowptr = fillc + NNODES;                       // N+1
    int* bsum   = rowptr + NNODES + 1;                  // 256
    int* colv   = bsum + 256;                           // E
    int* pose   = colv + NEDGES;                        // E (edge within-row positions)

    hipMemsetAsync(deg, 0, 2 * NNODES * sizeof(int), stream);

    const int NB = (NNODES + 255) / 256;   // 196

    count_deg_tw_k<<<EB + TB, 256, 0, stream>>>(dstv, deg, pose, W1, W1t, W2, W2t, Wm1, W1mt, Wm2, W2mt);
    blocksum_k<<<NB, 256, 0, stream>>>(deg, bsum);
    scan_write_k<<<NB, 256, 0, stream>>>(deg, bsum, rowptr);

    // fused: fill_csr (EB blocks, atomic-free) + l1 (2*MBD blocks) — one dispatch
    fill_l1_k<<<EB + 2 * MBD, 256, 0, stream>>>(srcv, dstv, rowptr, pose, colv,
                                                x, W1t, att_s1, att_d1, h1b, as1, ad1);

    // head-partitioned: 8 heads x ceil(N/32) node-chunks; head = blockIdx & 7 -> XCD id
    gat1_agg_k<<<8 * ((NNODES + 31) / 32), 256, 0, stream>>>(h1b, as1, ad1, rowptr, colv, b1, hL1b);

    l2_k<<<MBD, 256, 0, stream>>>(hL1b, W2t, att_s2, att_d2, h2b, as2, ad2);
    gat2_agg_k<<<NNODES / 4, 256, 0, stream>>>(h2b, as2, ad2, rowptr, colv, b2, emb_out);

    mlp_mfma_k<<<MBD, 256, 0, stream>>>(emb_out, W1mt, bm1, W2mt, bm2, out);
}

// Round 12
// 226.360 us; speedup vs baseline: 1.2069x; 1.0283x over previous
//
#include <hip/hip_runtime.h>
#include <hip/hip_fp16.h>
#include <math.h>

#define NNODES 50000
#define NEDGES 400000
#define INC    128
#define HC1    256   // HEADS*HID
#define NHEADS 8
#define OUTC   64
#define NK     16
#define NEG_SLOPE 0.2f
#define EPS_F  1e-16f

typedef unsigned short u16;
typedef __attribute__((ext_vector_type(8))) short bf16x8;
typedef __attribute__((ext_vector_type(4))) float f32x4;

__device__ __forceinline__ float lrelu(float x){ return x > 0.f ? x : NEG_SLOPE * x; }
__device__ __forceinline__ float eluf(float x){ return x > 0.f ? x : (__expf(x) - 1.f); }
__device__ __forceinline__ float bf2f(u16 v){ return __uint_as_float((unsigned)v << 16); }
__device__ __forceinline__ u16 f2bf(float f){
    unsigned u = __float_as_uint(f);
    unsigned r = (u + 0x7FFFu + ((u >> 16) & 1u)) >> 16;   // RTNE
    return (u16)r;
}
__device__ __forceinline__ short f2bf_s(float f){ return (short)f2bf(f); }
__device__ __forceinline__ u16 f2h(float f){ return __half_as_ushort(__float2half(f)); }
__device__ __forceinline__ float h2f(u16 v){ return __half2float(__ushort_as_half(v)); }

// hw packed f32x2 -> bf16x2 (RTNE), 1 instruction (no builtin on gfx950)
__device__ __forceinline__ unsigned cvtpk_bf16(float lo, float hi){
    unsigned r;
    asm("v_cvt_pk_bf16_f32 %0, %1, %2" : "=v"(r) : "v"(lo), "v"(hi));
    return r;
}

// one-instruction f16*f32+f32 MAC (no unpack)
__device__ __forceinline__ void fmix_lo(float& acc, unsigned w, float a){
    asm("v_fma_mix_f32 %0, %1, %2, %0 op_sel:[0,0,0] op_sel_hi:[1,0,0]"
        : "+v"(acc) : "v"(w), "v"(a));
}
__device__ __forceinline__ void fmix_hi(float& acc, unsigned w, float a){
    asm("v_fma_mix_f32 %0, %1, %2, %0 op_sel:[1,0,0] op_sel_hi:[1,0,0]"
        : "+v"(acc) : "v"(w), "v"(a));
}
__device__ __forceinline__ void mac8(float* acc, uint4 w, float a){
    fmix_lo(acc[0], w.x, a); fmix_hi(acc[1], w.x, a);
    fmix_lo(acc[2], w.y, a); fmix_hi(acc[3], w.y, a);
    fmix_lo(acc[4], w.z, a); fmix_hi(acc[5], w.z, a);
    fmix_lo(acc[6], w.w, a); fmix_hi(acc[7], w.w, a);
}
__device__ __forceinline__ void mac4(float4& acc, uint2 w, float a){
    fmix_lo(acc.x, w.x, a); fmix_hi(acc.y, w.x, a);
    fmix_lo(acc.z, w.y, a); fmix_hi(acc.w, w.y, a);
}

// ---------------- CSR build + weight prep ----------------
#define EB 1563   // ceil(400000/256)
#define TB 232    // ceil(59392/256)
#define MBD 782   // ceil(50000/64)
// count pass also records each edge's within-row position -> fill needs no atomics
__global__ void count_deg_tw_k(const int* __restrict__ dst, int* __restrict__ deg,
                               int* __restrict__ pose,
                               const float* __restrict__ W1, u16* __restrict__ W1t,
                               const float* __restrict__ W2, u16* __restrict__ W2t,
                               const float* __restrict__ Wm1, u16* __restrict__ W1mt,
                               const float* __restrict__ Wm2, u16* __restrict__ W2mt){
    if (blockIdx.x < EB){
        int e = blockIdx.x * 256 + threadIdx.x;
        if (e < NEDGES) pose[e] = atomicAdd(&deg[dst[e]], 1);
    } else {
        int i = (blockIdx.x - EB) * 256 + threadIdx.x;   // < 59392
        if (i < 32768){
            int n = i >> 7, k = i & 127;
            W1t[i] = f2bf(W1[k * 256 + n]);
        } else if (i < 49152){
            int ii = i - 32768;
            int n = ii >> 8, k = ii & 255;
            W2t[ii] = f2bf(W2[k * 64 + n]);
        } else if (i < 57344){
            int ii = i - 49152;
            int hd = ii >> 6, e = ii & 63;
            W1mt[ii] = f2bf(Wm1[e * 128 + hd]);
        } else if (i < 59392){
            int ii = i - 57344;
            int k = ii >> 7, hd = ii & 127;
            W2mt[ii] = f2bf(Wm2[hd * NK + k]);
        }
    }
}

__global__ void blocksum_k(const int* __restrict__ deg, int* __restrict__ bsum){
    __shared__ int sm[4];
    int i = blockIdx.x * 256 + threadIdx.x;
    int v = (i < NNODES) ? deg[i] : 0;
    for (int off = 1; off < 64; off <<= 1) v += __shfl_xor(v, off);
    int lane = threadIdx.x & 63, wid = threadIdx.x >> 6;
    if (lane == 0) sm[wid] = v;
    __syncthreads();
    if (threadIdx.x == 0) bsum[blockIdx.x] = sm[0] + sm[1] + sm[2] + sm[3];
}

__global__ void scan_write_k(const int* __restrict__ deg, const int* __restrict__ bsum,
                             int* __restrict__ rowptr){
    __shared__ int sm[4];
    __shared__ int sadd;
    int tid = threadIdx.x;
    int pv = (tid < blockIdx.x) ? bsum[tid] : 0;   // NB=196 < 256
    for (int off = 1; off < 64; off <<= 1) pv += __shfl_xor(pv, off);
    int lane = tid & 63, wid = tid >> 6;
    if (lane == 0) sm[wid] = pv;
    __syncthreads();
    if (tid == 0) sadd = sm[0] + sm[1] + sm[2] + sm[3];
    __syncthreads();

    int i = blockIdx.x * 256 + tid;
    int v = (i < NNODES) ? deg[i] : 0;
    int sv = v;
    for (int off = 1; off < 64; off <<= 1){ int t = __shfl_up(sv, off); if (lane >= off) sv += t; }
    __shared__ int wsum[4];
    if (lane == 63) wsum[wid] = sv;
    __syncthreads();
    int add = sadd;
    for (int w = 0; w < wid; w++) add += wsum[w];
    sv += add;
    if (i < NNODES) rowptr[i + 1] = sv;
    if (i == 0) rowptr[0] = 0;
}

// ---------------- FUSED: fill_csr (blocks 0..EB-1, atomic-free) + L1 ----------------
// L1: h1bh[8][N][32] = f16(x @ W1) head-major, fused att1.
// l1 branch pre-issues all 8 x-float4 loads before staging (load MLP), converts with
// v_cvt_pk_bf16_f32 after the barrier.
__global__ __launch_bounds__(256, 4) void fill_l1_k(
        const int* __restrict__ src, const int* __restrict__ dstv,
        const int* __restrict__ rowptr, const int* __restrict__ pose, int* __restrict__ col,
        const float* __restrict__ x, const u16* __restrict__ W1t,
        const float* __restrict__ att_s, const float* __restrict__ att_d,
        u16* __restrict__ h1bh, float* __restrict__ as1h, float* __restrict__ ad1h){
    __shared__ u16 Bs[16384];   // 32 KB (l1 branch only)
    if (blockIdx.x < EB){
        int e = blockIdx.x * 256 + threadIdx.x;
        if (e < NEDGES){
            int d = dstv[e];
            col[rowptr[d] + pose[e]] = src[e];   // non-atomic scatter
        }
        return;
    }
    int li = blockIdx.x - EB;             // 0..2*MBD-1
    int by = (li >= MBD) ? 1 : 0;
    int bx = li - by * MBD;

    int tid = threadIdx.x;
    int lane = tid & 63, wid = tid >> 6;
    int ln = lane & 15, quad = lane >> 4;
    int m0 = bx * 64 + wid * 16;
    int nb = by * 128;            // col base: 0 or 128
    int hb = by * 4;              // head base: 0 or 4
    int arow = m0 + ln; if (arow >= NNODES) arow = NNODES - 1;

    // (1) pre-issue ALL x loads (8 float4 = 32 VGPR) so they fly with staging
    const float* xb = x + (size_t)arow * INC + quad * 8;
    float4 xv0[4], xv1[4];
#pragma unroll
    for (int kt = 0; kt < 4; kt++){
        xv0[kt] = *(const float4*)(xb + kt * 32);
        xv1[kt] = *(const float4*)(xb + kt * 32 + 4);
    }

    // (2) stage W1t[nb..nb+128) into LDS (fragment order); 8 independent 16B loads/thread
#pragma unroll
    for (int it = 0; it < 8; it++){
        int p = it * 256 + tid;          // 0..2047
        int c = p >> 6, l = p & 63;
        int snt = c & 7, skt = c >> 3;
        int sln = l & 15, sq = l >> 4;
        uint4 v = *(const uint4*)(W1t + (size_t)(nb + snt * 16 + sln) * INC + skt * 32 + sq * 8);
        *(uint4*)(&Bs[p * 8]) = v;
    }

    __syncthreads();

    // (3) convert x -> bf16 frags with packed hw converts (1 instr / 2 vals)
    bf16x8 a[4];
#pragma unroll
    for (int kt = 0; kt < 4; kt++){
        union { unsigned u[4]; bf16x8 v; } cv;
        cv.u[0] = cvtpk_bf16(xv0[kt].x, xv0[kt].y);
        cv.u[1] = cvtpk_bf16(xv0[kt].z, xv0[kt].w);
        cv.u[2] = cvtpk_bf16(xv1[kt].x, xv1[kt].y);
        cv.u[3] = cvtpk_bf16(xv1[kt].z, xv1[kt].w);
        a[kt] = cv.v;
    }

    f32x4 acc[8];
#pragma unroll
    for (int nt = 0; nt < 8; nt++) acc[nt] = (f32x4){0.f, 0.f, 0.f, 0.f};

#pragma unroll
    for (int kt = 0; kt < 4; kt++){
#pragma unroll
        for (int nt = 0; nt < 8; nt++){
            bf16x8 b = *(const bf16x8*)(&Bs[(kt * 8 + nt) * 512 + lane * 8]);
            acc[nt] = __builtin_amdgcn_mfma_f32_16x16x32_bf16(a[kt], b, acc[nt], 0, 0, 0);
        }
    }

    // h1b write: head-major [h][N][32] f16
#pragma unroll
    for (int i = 0; i < 4; i++){
        int r = m0 + quad * 4 + i;
        if (r < NNODES){
#pragma unroll
            for (int nt = 0; nt < 8; nt++){
                int c  = nb + nt * 16 + ln;      // global channel
                int hh = c >> 5, c5 = c & 31;
                h1bh[((size_t)hh * NNODES + r) * 32 + c5] = f2h(acc[nt][i]);
            }
        }
    }

#pragma unroll
    for (int i = 0; i < 4; i++){
        int r = m0 + quad * 4 + i;
        float ps_keep = 0.f, pd_keep = 0.f;
#pragma unroll
        for (int h = 0; h < 4; h++){
            float ps = acc[2 * h][i]     * att_s[nb + h * 32 + ln]
                     + acc[2 * h + 1][i] * att_s[nb + h * 32 + 16 + ln];
            float pd = acc[2 * h][i]     * att_d[nb + h * 32 + ln]
                     + acc[2 * h + 1][i] * att_d[nb + h * 32 + 16 + ln];
            ps += __shfl_xor(ps, 1); pd += __shfl_xor(pd, 1);
            ps += __shfl_xor(ps, 2); pd += __shfl_xor(pd, 2);
            ps += __shfl_xor(ps, 4); pd += __shfl_xor(pd, 4);
            ps += __shfl_xor(ps, 8); pd += __shfl_xor(pd, 8);
            if (ln == h){ ps_keep = ps; pd_keep = pd; }
        }
        if (ln < 4 && r < NNODES){
            as1h[(size_t)(hb + ln) * NNODES + r] = ps_keep;
            ad1h[(size_t)(hb + ln) * NNODES + r] = pd_keep;
        }
    }
}

// ---------------- L2: h2b[N,64] = f16(hL1b @ W2), fused att2 (LDS-staged B) ----------
// hL1b is head-major [8][N][32] bf16: A-frag for k-tile kt = head kt.
__global__ __launch_bounds__(256, 4) void l2_k(const u16* __restrict__ hL1b, const u16* __restrict__ W2t,
                     const float* __restrict__ att_s, const float* __restrict__ att_d,
                     u16* __restrict__ h2b, float* __restrict__ as2, float* __restrict__ ad2){
    __shared__ u16 Bs[16384];   // 32 KB: chunk c=(kt*4+nt), kt in [0,8), nt in [0,4)
    int tid = threadIdx.x;
    int lane = tid & 63, wid = tid >> 6;
    int ln = lane & 15, quad = lane >> 4;
    int m0 = blockIdx.x * 64 + wid * 16;
    int arow = m0 + ln; if (arow >= NNODES) arow = NNODES - 1;

#pragma unroll
    for (int it = 0; it < 8; it++){
        int p = it * 256 + tid;          // 0..2047
        int c = p >> 6, l = p & 63;
        int snt = c & 3, skt = c >> 2;
        int sln = l & 15, sq = l >> 4;
        uint4 v = *(const uint4*)(W2t + (size_t)(snt * 16 + sln) * HC1 + skt * 32 + sq * 8);
        *(uint4*)(&Bs[p * 8]) = v;
    }

    __syncthreads();

    f32x4 acc[4];
#pragma unroll
    for (int nt = 0; nt < 4; nt++) acc[nt] = (f32x4){0.f, 0.f, 0.f, 0.f};

#pragma unroll
    for (int kt = 0; kt < 8; kt++){
        bf16x8 a = *(const bf16x8*)(hL1b + ((size_t)kt * NNODES + arow) * 32 + quad * 8);
#pragma unroll
        for (int nt = 0; nt < 4; nt++){
            bf16x8 b = *(const bf16x8*)(&Bs[(kt * 4 + nt) * 512 + lane * 8]);
            acc[nt] = __builtin_amdgcn_mfma_f32_16x16x32_bf16(a, b, acc[nt], 0, 0, 0);
        }
    }

#pragma unroll
    for (int i = 0; i < 4; i++){
        int r = m0 + quad * 4 + i;
        if (r < NNODES){
#pragma unroll
            for (int nt = 0; nt < 4; nt++)
                h2b[(size_t)r * OUTC + nt * 16 + ln] = f2h(acc[nt][i]);
        }
        float ps = acc[0][i] * att_s[ln]      + acc[1][i] * att_s[16 + ln]
                 + acc[2][i] * att_s[32 + ln] + acc[3][i] * att_s[48 + ln];
        float pd = acc[0][i] * att_d[ln]      + acc[1][i] * att_d[16 + ln]
                 + acc[2][i] * att_d[32 + ln] + acc[3][i] * att_d[48 + ln];
        ps += __shfl_xor(ps, 1); pd += __shfl_xor(pd, 1);
        ps += __shfl_xor(ps, 2); pd += __shfl_xor(pd, 2);
        ps += __shfl_xor(ps, 4); pd += __shfl_xor(pd, 4);
        ps += __shfl_xor(ps, 8); pd += __shfl_xor(pd, 8);
        if (ln == 0 && r < NNODES){ as2[r] = ps; ad2[r] = pd; }
    }
}

// ---------------- GAT layer 1 aggregation: head-partitioned, no-max softmax, --------
// late normalization. 8-lane group per (dst,head); rows fetched as uint4 x 4 lanes
// (2 rows per gather instruction -> half the divergent-address instructions vs uint2).
__global__ void gat1_agg_k(const u16* __restrict__ h1bh, const float* __restrict__ as1h,
                           const float* __restrict__ ad1h, const int* __restrict__ rowptr,
                           const int* __restrict__ col, const float* __restrict__ b1,
                           u16* __restrict__ outb){
    int lane = threadIdx.x & 63, wid = threadIdx.x >> 6;
    int g = lane >> 3, t = lane & 7;
    int team = t >> 2, tql = t & 3;      // 2 teams of 4 lanes; lane covers 16B of a 64B row
    int h = blockIdx.x & 7;
    int d = (blockIdx.x >> 3) * 32 + wid * 8 + g;
    bool valid = (d < NNODES);
    int dd = valid ? d : (NNODES - 1);
    int row0 = rowptr[dd];
    int deg  = rowptr[dd + 1] - row0;

    const float* ash = as1h + (size_t)h * NNODES;
    float adst = ad1h[(size_t)h * NNODES + dd];
    const u16* hb = h1bh + (size_t)h * NNODES * 32;

    // col loads (round 1), then score gathers + self row (round 2, concurrent)
    int sv0 = (t < deg)     ? col[row0 + t]     : dd;
    int sv1 = (8 + t < deg) ? col[row0 + 8 + t] : dd;
    uint4 wself = *(const uint4*)(hb + (size_t)dd * 32 + tql * 8);
    float ev0 = ash[sv0];
    float ev1 = ash[sv1];

    float a_self = __expf(lrelu(ash[dd] + adst));
    float x0 = (t < deg)     ? __expf(lrelu(ev0 + adst)) : 0.f;
    float x1 = (8 + t < deg) ? __expf(lrelu(ev1 + adst)) : 0.f;

    float acc[8] = {0.f, 0.f, 0.f, 0.f, 0.f, 0.f, 0.f, 0.f};
    mac8(acc, wself, team ? 0.f : a_self);

    int gb = g * 8;
    // edges 0-7: 4 pairs; pair p covers edges (2p, 2p+1) -> team 0/1 rows
    if (deg > 0){
        int s0 = __shfl(sv0, gb + 0 + team); float a0 = __shfl(x0, gb + 0 + team);
        int s1 = __shfl(sv0, gb + 2 + team); float a1 = __shfl(x0, gb + 2 + team);
        uint4 w0 = *(const uint4*)(hb + (size_t)s0 * 32 + tql * 8);
        uint4 w1 = *(const uint4*)(hb + (size_t)s1 * 32 + tql * 8);
        mac8(acc, w0, a0);
        mac8(acc, w1, a1);
        if (deg > 4){
            int s2 = __shfl(sv0, gb + 4 + team); float a2 = __shfl(x0, gb + 4 + team);
            int s3 = __shfl(sv0, gb + 6 + team); float a3 = __shfl(x0, gb + 6 + team);
            uint4 w2 = *(const uint4*)(hb + (size_t)s2 * 32 + tql * 8);
            uint4 w3 = *(const uint4*)(hb + (size_t)s3 * 32 + tql * 8);
            mac8(acc, w2, a2);
            mac8(acc, w3, a3);
        }
    }
    if (deg > 8){
        int s0 = __shfl(sv1, gb + 0 + team); float a0 = __shfl(x1, gb + 0 + team);
        int s1 = __shfl(sv1, gb + 2 + team); float a1 = __shfl(x1, gb + 2 + team);
        uint4 w0 = *(const uint4*)(hb + (size_t)s0 * 32 + tql * 8);
        uint4 w1 = *(const uint4*)(hb + (size_t)s1 * 32 + tql * 8);
        mac8(acc, w0, a0);
        mac8(acc, w1, a1);
        if (deg > 12){
            int s2 = __shfl(sv1, gb + 4 + team); float a2 = __shfl(x1, gb + 4 + team);
            int s3 = __shfl(sv1, gb + 6 + team); float a3 = __shfl(x1, gb + 6 + team);
            uint4 w2 = *(const uint4*)(hb + (size_t)s2 * 32 + tql * 8);
            uint4 w3 = *(const uint4*)(hb + (size_t)s3 * 32 + tql * 8);
            mac8(acc, w2, a2);
            mac8(acc, w3, a3);
        }
    }
    float tsum = 0.f;
    if (deg > 16){
        for (int idx = 16; idx < deg; idx++){
            int s = col[row0 + idx];   // group-uniform
            float a = __expf(lrelu(ash[s] + adst));
            tsum += a;                 // uniform across the 8-lane group
            uint4 w = *(const uint4*)(hb + (size_t)s * 32 + tql * 8);
            mac8(acc, w, team ? 0.f : a);   // team 0 only (avoid double-count)
        }
    }

    // vsum reduction AFTER the MACs (off the critical path)
    float part = x0 + x1;
    part += __shfl_xor(part, 1);
    part += __shfl_xor(part, 2);
    part += __shfl_xor(part, 4);
    float rden = 1.f / (part + a_self + tsum + EPS_F);

    // combine teams: channels tql*8..+7 held by lanes t=tql and t=tql+4
#pragma unroll
    for (int k = 0; k < 8; k++) acc[k] += __shfl_xor(acc[k], 4);

    if (valid && team == 0){
        const float* bp = b1 + h * 32 + tql * 8;
        float4 b0 = *(const float4*)bp;
        float4 b4 = *(const float4*)(bp + 4);
        uint4 o;
        o.x = (unsigned)f2bf(eluf(acc[0] * rden + b0.x)) | ((unsigned)f2bf(eluf(acc[1] * rden + b0.y)) << 16);
        o.y = (unsigned)f2bf(eluf(acc[2] * rden + b0.z)) | ((unsigned)f2bf(eluf(acc[3] * rden + b0.w)) << 16);
        o.z = (unsigned)f2bf(eluf(acc[4] * rden + b4.x)) | ((unsigned)f2bf(eluf(acc[5] * rden + b4.y)) << 16);
        o.w = (unsigned)f2bf(eluf(acc[6] * rden + b4.z)) | ((unsigned)f2bf(eluf(acc[7] * rden + b4.w)) << 16);
        *(uint4*)(outb + ((size_t)h * NNODES + d) * 32 + tql * 8) = o;
    }
}

// ---------------- GAT layer 2 aggregation: no-max softmax, late normalization --------
// (best measured; one edge-visit per edge, wave per dst)
__global__ void gat2_agg_k(const u16* __restrict__ h2b, const float* __restrict__ as2,
                           const float* __restrict__ ad2, const int* __restrict__ rowptr,
                           const int* __restrict__ col, const float* __restrict__ b2,
                           float* __restrict__ emb){
    int lane = threadIdx.x & 63, wid = threadIdx.x >> 6;
    int d = blockIdx.x * 4 + wid;
    int row0 = rowptr[d];
    int deg  = rowptr[d + 1] - row0;

    float adst = ad2[d];
    float a_self = __expf(lrelu(as2[d] + adst));

    if (deg <= 64){
        int sv = (lane < deg) ? col[row0 + lane] : d;
        float e_raw = as2[sv];   // score gather

        int q = lane >> 4, c4 = (lane & 15) * 4;
        // prefetch self + chunk-0 rows while exps compute
        uint2 wself = *(const uint2*)(h2b + (unsigned)d * OUTC + c4);
        uint2 wpre[4];
#pragma unroll
        for (int k = 0; k < 4; k++){
            int s = __shfl(sv, k * 4 + q);
            wpre[k] = *(const uint2*)(h2b + (unsigned)s * OUTC + c4);
        }

        float x = (lane < deg) ? __expf(lrelu(e_raw + adst)) : 0.f;  // un-normalized alpha

        float a0 = (q == 0) ? a_self : 0.f;
        float4 acc = make_float4(0.f, 0.f, 0.f, 0.f);
        mac4(acc, wself, a0);
        // chunk 0 from prefetch
        {
            float a_arr[4];
#pragma unroll
            for (int k = 0; k < 4; k++) a_arr[k] = __shfl(x, k * 4 + q);
#pragma unroll
            for (int k = 0; k < 4; k++) mac4(acc, wpre[k], a_arr[k]);
        }
        for (int it0 = 16; it0 < deg; it0 += 16){
            int s_arr[4]; float a_arr[4];
#pragma unroll
            for (int k = 0; k < 4; k++){
                int itc = min(it0 + k * 4 + q, 63);
                s_arr[k] = __shfl(sv, itc);
                a_arr[k] = __shfl(x, itc);
            }
            uint2 w_arr[4];
#pragma unroll
            for (int k = 0; k < 4; k++)
                w_arr[k] = *(const uint2*)(h2b + (unsigned)s_arr[k] * OUTC + c4);
#pragma unroll
            for (int k = 0; k < 4; k++) mac4(acc, w_arr[k], a_arr[k]);
        }
        // channel reduce + vsum reduce (both after MACs)
        acc.x += __shfl_xor(acc.x, 16); acc.y += __shfl_xor(acc.y, 16);
        acc.z += __shfl_xor(acc.z, 16); acc.w += __shfl_xor(acc.w, 16);
        acc.x += __shfl_xor(acc.x, 32); acc.y += __shfl_xor(acc.y, 32);
        acc.z += __shfl_xor(acc.z, 32); acc.w += __shfl_xor(acc.w, 32);
        float vsum = x;
        for (int m = 1; m < 64; m <<= 1) vsum += __shfl_xor(vsum, m);
        float rden = 1.f / (vsum + a_self + EPS_F);
        if (lane < 16){
            float4 bb = *(const float4*)(b2 + c4);
            float4 o = make_float4(acc.x * rden + bb.x, acc.y * rden + bb.y,
                                   acc.z * rden + bb.z, acc.w * rden + bb.w);
            *(float4*)(emb + (size_t)d * OUTC + c4) = o;
        }
    } else {
        // single-pass: uniform per-edge alpha, lane owns one channel
        float vsum = a_self;
        float acc = a_self * h2f(h2b[(unsigned)d * OUTC + lane]);
        for (int idx = 0; idx < deg; idx++){
            int s = col[row0 + idx];
            float a = __expf(lrelu(as2[s] + adst));
            vsum += a;
            acc += a * h2f(h2b[(unsigned)s * OUTC + lane]);
        }
        emb[(size_t)d * OUTC + lane] = acc * (1.f / (vsum + EPS_F)) + b2[lane];
    }
}

// ---------------- MLP head + softmax via MFMA ----------------
__global__ void mlp_mfma_k(const float* __restrict__ emb, const u16* __restrict__ W1mt,
                           const float* __restrict__ bm1, const u16* __restrict__ W2mt,
                           const float* __restrict__ bm2, float* __restrict__ sout){
    __shared__ u16 hid[4][16][136];
    int lane = threadIdx.x & 63, wid = threadIdx.x >> 6;
    int ln = lane & 15, quad = lane >> 4;
    int m0 = blockIdx.x * 64 + wid * 16;
    int arow = m0 + ln; if (arow >= NNODES) arow = NNODES - 1;

    bf16x8 a[2];
#pragma unroll
    for (int kt = 0; kt < 2; kt++){
        const float* ap = emb + (size_t)arow * OUTC + kt * 32 + quad * 8;
        float4 v0 = *(const float4*)ap;
        float4 v1 = *(const float4*)(ap + 4);
        union { unsigned u[4]; bf16x8 v; } cv;
        cv.u[0] = cvtpk_bf16(v0.x, v0.y);
        cv.u[1] = cvtpk_bf16(v0.z, v0.w);
        cv.u[2] = cvtpk_bf16(v1.x, v1.y);
        cv.u[3] = cvtpk_bf16(v1.z, v1.w);
        a[kt] = cv.v;
    }

    f32x4 acc[8];
#pragma unroll
    for (int nt = 0; nt < 8; nt++) acc[nt] = (f32x4){0.f, 0.f, 0.f, 0.f};
#pragma unroll
    for (int kt = 0; kt < 2; kt++){
#pragma unroll
        for (int nt = 0; nt < 8; nt++){
            bf16x8 b = *(const bf16x8*)(W1mt + (size_t)(nt * 16 + ln) * OUTC + kt * 32 + quad * 8);
            acc[nt] = __builtin_amdgcn_mfma_f32_16x16x32_bf16(a[kt], b, acc[nt], 0, 0, 0);
        }
    }

#pragma unroll
    for (int nt = 0; nt < 8; nt++){
        float bb = bm1[nt * 16 + ln];
#pragma unroll
        for (int i = 0; i < 4; i++){
            float h = fmaxf(acc[nt][i] + bb, 0.f);
            hid[wid][quad * 4 + i][nt * 16 + ln] = f2bf(h);
        }
    }

    f32x4 acc2 = (f32x4){0.f, 0.f, 0.f, 0.f};
#pragma unroll
    for (int kt = 0; kt < 4; kt++){
        bf16x8 ah = *(const bf16x8*)&hid[wid][ln][kt * 32 + quad * 8];
        bf16x8 bw = *(const bf16x8*)(W2mt + (size_t)ln * 128 + kt * 32 + quad * 8);
        acc2 = __builtin_amdgcn_mfma_f32_16x16x32_bf16(ah, bw, acc2, 0, 0, 0);
    }

    float bcl = bm2[ln];
#pragma unroll
    for (int i = 0; i < 4; i++){
        int r = m0 + quad * 4 + i;
        float lg = acc2[i] + bcl;
        float m = lg;
        m = fmaxf(m, __shfl_xor(m, 1));
        m = fmaxf(m, __shfl_xor(m, 2));
        m = fmaxf(m, __shfl_xor(m, 4));
        m = fmaxf(m, __shfl_xor(m, 8));
        float ex = __expf(lg - m);
        float s = ex;
        s += __shfl_xor(s, 1);
        s += __shfl_xor(s, 2);
        s += __shfl_xor(s, 4);
        s += __shfl_xor(s, 8);
        if (r < NNODES) sout[(size_t)r * NK + ln] = ex / s;
    }
}

// ---------------- launcher ----------------
extern "C" void kernel_launch(void* const* d_in, const int* in_sizes, int n_in,
                              void* d_out, int out_size, void* d_ws, size_t ws_size,
                              hipStream_t stream){
    const float* x      = (const float*)d_in[0];
    const int*   ei     = (const int*)d_in[1];
    const int*   srcv   = ei;
    const int*   dstv   = ei + NEDGES;
    const float* W1     = (const float*)d_in[2];
    const float* att_s1 = (const float*)d_in[3];
    const float* att_d1 = (const float*)d_in[4];
    const float* b1     = (const float*)d_in[5];
    const float* W2     = (const float*)d_in[6];
    const float* att_s2 = (const float*)d_in[7];
    const float* att_d2 = (const float*)d_in[8];
    const float* b2     = (const float*)d_in[9];
    const float* Wm1    = (const float*)d_in[10];
    const float* bm1    = (const float*)d_in[11];
    const float* Wm2    = (const float*)d_in[12];
    const float* bm2    = (const float*)d_in[13];

    float* out     = (float*)d_out;                     // s: [N,16]
    float* emb_out = out + (size_t)NNODES * NK;         // embeddings: [N,64]

    u16* h1b   = (u16*)d_ws;                            // [8][N][32] f16
    u16* hL1b  = h1b  + (size_t)NNODES * HC1;           // [8][N][32] bf16
    u16* h2b   = hL1b + (size_t)NNODES * HC1;           // N*64 f16 (row-major)
    u16* W1t   = h2b  + (size_t)NNODES * OUTC;          // 256*128
    u16* W2t   = W1t + 256 * 128;                       // 64*256
    u16* W1mt  = W2t + 64 * 256;                        // 128*64
    u16* W2mt  = W1mt + 128 * 64;                       // 16*128
    float* as1 = (float*)(W2mt + 16 * 128);             // [8][N]
    float* ad1 = as1 + (size_t)NNODES * NHEADS;         // [8][N]
    float* as2 = ad1 + (size_t)NNODES * NHEADS;         // N
    float* ad2 = as2 + NNODES;                          // N
    int* deg    = (int*)(ad2 + NNODES);                 // N   (deg+fillc adjacent -> 1 memset)
    int* fillc  = deg + NNODES;                         // N (unused now, kept for layout)
    int* rowptr = fillc + NNODES;                       // N+1
    int* bsum   = rowptr + NNODES + 1;                  // 256
    int* colv   = bsum + 256;                           // E
    int* pose   = colv + NEDGES;                        // E (edge within-row positions)

    hipMemsetAsync(deg, 0, 2 * NNODES * sizeof(int), stream);

    const int NB = (NNODES + 255) / 256;   // 196

    count_deg_tw_k<<<EB + TB, 256, 0, stream>>>(dstv, deg, pose, W1, W1t, W2, W2t, Wm1, W1mt, Wm2, W2mt);
    blocksum_k<<<NB, 256, 0, stream>>>(deg, bsum);
    scan_write_k<<<NB, 256, 0, stream>>>(deg, bsum, rowptr);

    // fused: fill_csr (EB blocks, atomic-free) + l1 (2*MBD blocks) — one dispatch
    fill_l1_k<<<EB + 2 * MBD, 256, 0, stream>>>(srcv, dstv, rowptr, pose, colv,
                                                x, W1t, att_s1, att_d1, h1b, as1, ad1);

    // head-partitioned: 8 heads x ceil(N/32) node-chunks; head = blockIdx & 7 -> XCD id
    gat1_agg_k<<<8 * ((NNODES + 31) / 32), 256, 0, stream>>>(h1b, as1, ad1, rowptr, colv, b1, hL1b);

    l2_k<<<MBD, 256, 0, stream>>>(hL1b, W2t, att_s2, att_d2, h2b, as2, ad2);
    gat2_agg_k<<<NNODES / 4, 256, 0, stream>>>(h2b, as2, ad2, rowptr, colv, b2, emb_out);

    mlp_mfma_k<<<MBD, 256, 0, stream>>>(emb_out, W1mt, bm1, W2mt, bm2, out);
}